// Round 2
// baseline (4722.245 us; speedup 1.0000x reference)
//
#include <hip/hip_runtime.h>

// ---------------- problem constants ----------------
#define NB 2048
#define ND 1024
#define NS 30720
#define K_MAIN 131072LL           // TOP_K * B
#define K_AUX  2097152LL          // TOP_K * AUX_K_MULT * B
#define CAND_CAP 262144
#define SEL_CAP  4096

// ---------------- ws layout (bytes) ----------------
#define OFF_SCAL 0                // int[64]
#define OFF_ACC  256              // double[8]
#define OFF_H1M  512              // int[4096]
#define OFF_H1A  (512 + 16384)
#define OFF_H2M  (512 + 32768)
#define OFF_H2A  (512 + 49152)
#define OFF_ZERO_END (512 + 65536)    // 66048 — zeroed every launch
#define OFF_DEAD 66048                // 30720 bytes
#define OFF_SEL_IDX 98304             // int[SEL_CAP]
#define OFF_SEL_BITS (98304 + 16384)  // uint[SEL_CAP]
#define OFF_CMB  131072               // uint[CAND_CAP]
#define OFF_CMI  (OFF_CMB + CAND_CAP*4)
#define OFF_CAB  (OFF_CMI + CAND_CAP*4)
#define OFF_CAI  (OFF_CAB + CAND_CAP*4)

// scal indices
#define S_NDEAD 0
#define S_B1M 1
#define S_REM1M 2
#define S_B1A 3
#define S_REM1A 4
#define S_T24M 6
#define S_JM 7
#define S_T24A 8
#define S_JA 9
#define S_CCM 10
#define S_CCA 11
#define S_SELCNT 12
#define S_L0 13
#define S_MINBITS 14

// acc indices
#define A_L2_0 0
#define A_L1 4
#define A_AUX 5

// ---------------- helpers ----------------
__device__ __forceinline__ float blk_reduce(float v, float* sred) {
    int t = threadIdx.x;
    #pragma unroll
    for (int o = 32; o > 0; o >>= 1) v += __shfl_down(v, o, 64);
    __syncthreads();
    if ((t & 63) == 0) sred[t >> 6] = v;
    __syncthreads();
    return sred[0] + sred[1] + sred[2] + sred[3];
}

// ---------------- kernels ----------------
__global__ void k_init(int* w) {
    int n = OFF_ZERO_END / 4;
    for (int i = blockIdx.x * blockDim.x + threadIdx.x; i < n; i += gridDim.x * blockDim.x)
        w[i] = 0;
}

__global__ void k_dead(const int* __restrict__ nbna, unsigned char* __restrict__ dead, int* scal) {
    int stride = gridDim.x * blockDim.x;
    int cnt = 0;
    for (int i = blockIdx.x * blockDim.x + threadIdx.x; i < NS; i += stride) {
        bool d = nbna[i] >= 20;
        dead[i] = d ? 1 : 0;
        cnt += d ? 1 : 0;
    }
    #pragma unroll
    for (int o = 32; o > 0; o >>= 1) cnt += __shfl_down(cnt, o, 64);
    if ((threadIdx.x & 63) == 0 && cnt) atomicAdd(&scal[S_NDEAD], cnt);
}

// encoder GEMM with FP64 accumulation: acts = relu((x - b_dec) @ W_enc + b_enc)
// fp64 eliminates top-k boundary flips vs the fp64 numpy reference (inter-order-
// statistic gap at the k-th value is ~3.4e-6; fp64 accumulation error ~1e-13 rel).
#define GBM 128
#define GBN 128
#define GBK 8
__global__ __launch_bounds__(256) void k_enc_gemm(const float* __restrict__ x,
        const float* __restrict__ b_dec, const float* __restrict__ b_enc,
        const float* __restrict__ W, float* __restrict__ acts) {
    __shared__ double As[GBK][GBM];
    __shared__ double Bs[GBK][GBN];
    const int t = threadIdx.x;
    const int tx = t & 15, ty = t >> 4;
    const int m0 = blockIdx.y * GBM, n0 = blockIdx.x * GBN;
    const int am = t >> 1, ak = (t & 1) * 4;
    const int bk = t >> 5, bnq = (t & 31) * 4;

    double acc[8][8];
    #pragma unroll
    for (int i = 0; i < 8; i++)
        #pragma unroll
        for (int j = 0; j < 8; j++) acc[i][j] = 0.0;

    for (int k0 = 0; k0 < ND; k0 += GBK) {
        float4 av = *(const float4*)(x + (size_t)(m0 + am) * ND + k0 + ak);
        float4 bd = *(const float4*)(b_dec + k0 + ak);
        As[ak + 0][am] = (double)av.x - (double)bd.x;
        As[ak + 1][am] = (double)av.y - (double)bd.y;
        As[ak + 2][am] = (double)av.z - (double)bd.z;
        As[ak + 3][am] = (double)av.w - (double)bd.w;
        float4 wv = *(const float4*)(W + (size_t)(k0 + bk) * NS + n0 + bnq);
        Bs[bk][bnq + 0] = (double)wv.x;
        Bs[bk][bnq + 1] = (double)wv.y;
        Bs[bk][bnq + 2] = (double)wv.z;
        Bs[bk][bnq + 3] = (double)wv.w;
        __syncthreads();
        #pragma unroll
        for (int kk = 0; kk < GBK; kk++) {
            double a[8], b[8];
            #pragma unroll
            for (int i = 0; i < 8; i++) a[i] = As[kk][ty * 8 + i];
            #pragma unroll
            for (int j = 0; j < 8; j++) b[j] = Bs[kk][tx * 8 + j];
            #pragma unroll
            for (int i = 0; i < 8; i++)
                #pragma unroll
                for (int j = 0; j < 8; j++)
                    acc[i][j] = fma(a[i], b[j], acc[i][j]);
        }
        __syncthreads();
    }
    #pragma unroll
    for (int i = 0; i < 8; i++) {
        float* orow = acts + (size_t)(m0 + ty * 8 + i) * NS + n0 + tx * 8;
        #pragma unroll
        for (int j = 0; j < 8; j++) {
            double v = acc[i][j] + (double)b_enc[n0 + tx * 8 + j];
            orow[j] = (float)fmax(v, 0.0);
        }
    }
}

// fused coarse histograms: main (all) + aux (dead cols only); bins = bits >> 20
__global__ __launch_bounds__(256) void k_hist1(const float* __restrict__ acts,
        const unsigned char* __restrict__ dead, int* h1m, int* h1a) {
    __shared__ int hm[4096], ha[4096];
    int t = threadIdx.x;
    for (int i = t; i < 4096; i += 256) { hm[i] = 0; ha[i] = 0; }
    __syncthreads();
    for (int row = blockIdx.x; row < NB; row += gridDim.x) {
        const float* pr = acts + (size_t)row * NS;
        for (int c = t; c < NS; c += 256) {
            unsigned bits = __float_as_uint(pr[c]);
            bool isz = (bits == 0u);
            bool dd = dead[c] != 0;
            unsigned long long mz = __ballot(isz);
            unsigned long long mza = __ballot(isz && dd);
            if ((t & 63) == 0) {
                int nz = __popcll(mz);
                if (nz) atomicAdd(&hm[0], nz);
                int nza = __popcll(mza);
                if (nza) atomicAdd(&ha[0], nza);
            }
            if (!isz) {
                atomicAdd(&hm[bits >> 20], 1);
                if (dd) atomicAdd(&ha[bits >> 20], 1);
            }
        }
    }
    __syncthreads();
    for (int i = t; i < 4096; i += 256) {
        if (hm[i]) atomicAdd(&h1m[i], hm[i]);
        if (ha[i]) atomicAdd(&h1a[i], ha[i]);
    }
}

// generic suffix-scan over a 4096-bin histogram; finds bin containing rank k (from top)
__global__ void k_scan(const int* __restrict__ hist, int* scal, int mode) {
    __shared__ long long csum[256];
    __shared__ long long totsh;
    int t = threadIdx.x;
    int base = t * 16;
    int h[16];
    long long loc = 0;
    #pragma unroll
    for (int i = 0; i < 16; i++) { h[i] = hist[base + i]; loc += h[i]; }
    csum[t] = loc;
    __syncthreads();
    if (t == 0) {
        long long run = 0;
        for (int c = 255; c >= 0; c--) { long long tmp = csum[c]; csum[c] = run; run += tmp; }
        totsh = run;
    }
    __syncthreads();
    long long k;
    if (mode == 0) k = K_MAIN;
    else if (mode == 1) k = K_AUX;
    else if (mode == 2) k = (long long)scal[S_REM1M];
    else {
        if (scal[S_B1A] < 0) { if (t == 0) { scal[S_T24A] = -1; scal[S_MINBITS] = 0; } return; }
        k = (long long)scal[S_REM1A];
    }
    if (mode == 1 && k > totsh) { if (t == 0) scal[S_B1A] = -1; return; }
    long long cum = csum[t];
    int fb = -1; long long rem = 0;
    for (int i = 15; i >= 0; i--) {
        long long ca = cum;
        cum += h[i];
        if (ca < k && k <= cum) { fb = base + i; rem = k - ca; }
    }
    if (fb >= 0) {
        if (mode == 0)      { scal[S_B1M] = fb; scal[S_REM1M] = (int)rem; }
        else if (mode == 1) { scal[S_B1A] = fb; scal[S_REM1A] = (int)rem; }
        else if (mode == 2) { scal[S_T24M] = (scal[S_B1M] << 12) | fb; scal[S_JM] = (int)rem; }
        else                { scal[S_T24A] = (scal[S_B1A] << 12) | fb; scal[S_JA] = (int)rem; }
    }
}

// fine histograms inside the selected coarse bins
__global__ __launch_bounds__(256) void k_hist2(const float* __restrict__ acts,
        const unsigned char* __restrict__ dead, const int* scal, int* h2m, int* h2a) {
    int b1m = scal[S_B1M], b1a = scal[S_B1A];
    int row = blockIdx.x, t = threadIdx.x;
    const float* pr = acts + (size_t)row * NS;
    for (int c = t; c < NS; c += 256) {
        unsigned bits = __float_as_uint(pr[c]);
        int hi = (int)(bits >> 20);
        if (hi == b1m) atomicAdd(&h2m[(bits >> 8) & 0xFFF], 1);
        if (b1a >= 0 && hi == b1a && dead[c]) atomicAdd(&h2a[(bits >> 8) & 0xFFF], 1);
    }
}

// collect boundary-bin candidates (24-bit prefix match)
__global__ __launch_bounds__(256) void k_collect(const float* __restrict__ acts,
        const unsigned char* __restrict__ dead, int* scal,
        unsigned* cmb, int* cmi, unsigned* cab, int* cai) {
    int t24m = scal[S_T24M], t24a = scal[S_T24A];
    int row = blockIdx.x, t = threadIdx.x;
    const float* pr = acts + (size_t)row * NS;
    for (int c = t; c < NS; c += 256) {
        unsigned bits = __float_as_uint(pr[c]);
        unsigned pre = bits >> 8;
        if (pre == (unsigned)t24m) {
            int p = atomicAdd(&scal[S_CCM], 1);
            if (p < CAND_CAP) { cmb[p] = bits; cmi[p] = row * NS + c; }
        }
        if (t24a >= 0 && pre == (unsigned)t24a && dead[c]) {
            int p = atomicAdd(&scal[S_CCA], 1);
            if (p < CAND_CAP) { cab[p] = bits; cai[p] = row * NS + c; }
        }
    }
}

// single block: resolve aux min_top_k_val exactly + build main selected list (jax tie-break: lowest index)
__global__ __launch_bounds__(256) void k_resolve(const unsigned* __restrict__ cmb, const int* __restrict__ cmi,
        const unsigned* __restrict__ cab, int* scal, int* sel_idx, unsigned* sel_bits) {
    __shared__ int h[256];
    __shared__ int tie_idx[2048];
    __shared__ int tiecnt, Lsh, cgtsh;
    int t = threadIdx.x;
    // ---- part A: aux threshold value ----
    h[t] = 0;
    __syncthreads();
    int t24a = scal[S_T24A];
    if (t24a >= 0) {
        int cnt = min(scal[S_CCA], CAND_CAP);
        int ja = scal[S_JA];
        for (int e = t; e < cnt; e += 256) atomicAdd(&h[cab[e] & 0xFF], 1);
        __syncthreads();
        if (t == 0) {
            long long cum = 0; int L = 0;
            for (int b = 255; b >= 0; b--) {
                long long ca = cum; cum += h[b];
                if (ca < ja && ja <= cum) { L = b; break; }
            }
            scal[S_MINBITS] = (int)((((unsigned)t24a) << 8) | (unsigned)L);
        }
    } else if (t == 0) scal[S_MINBITS] = 0;
    __syncthreads();
    // ---- part B: main selected list ----
    h[t] = 0;
    if (t == 0) tiecnt = 0;
    __syncthreads();
    int t24m = scal[S_T24M];
    int jm = scal[S_JM];
    if (jm <= 0) return;
    int cntm = min(scal[S_CCM], CAND_CAP);
    for (int e = t; e < cntm; e += 256) atomicAdd(&h[cmb[e] & 0xFF], 1);
    __syncthreads();
    if (t == 0) {
        long long cum = 0; int L = 0; long long cgt = 0;
        for (int b = 255; b >= 0; b--) {
            long long ca = cum; cum += h[b];
            if (ca < jm && jm <= cum) { L = b; cgt = ca; break; }
        }
        Lsh = L; cgtsh = (int)cgt;
    }
    __syncthreads();
    int L = Lsh;
    for (int e = t; e < cntm; e += 256) {
        int by = (int)(cmb[e] & 0xFF);
        if (by > L) {
            int p = atomicAdd(&scal[S_SELCNT], 1);
            if (p < SEL_CAP) { sel_idx[p] = cmi[e]; sel_bits[p] = cmb[e]; }
        } else if (by == L) {
            int p = atomicAdd(&tiecnt, 1);
            if (p < 2048) tie_idx[p] = e;
        }
    }
    __syncthreads();
    if (t == 0) {
        int tneed = jm - cgtsh;
        int m = min(tiecnt, 2048);
        unsigned vbits = (((unsigned)t24m) << 8) | (unsigned)L;
        for (int s = 0; s < tneed; s++) {
            int best = 0x7FFFFFFF, bi = -1;
            for (int q = 0; q < m; q++) {
                int e = tie_idx[q];
                if (e < 0) continue;
                int ix = cmi[e];
                if (ix < best) { best = ix; bi = q; }
            }
            if (bi < 0) break;
            tie_idx[bi] = -1;
            int p = atomicAdd(&scal[S_SELCNT], 1);
            if (p < SEL_CAP) { sel_idx[p] = best; sel_bits[p] = vbits; }
        }
    }
}

// hierarchical sparse decode: one block per row; top-k mask applied on the fly
__global__ __launch_bounds__(256) void k_decode(const float* __restrict__ acts,
        const float* __restrict__ x, const float* __restrict__ b_dec, const float* __restrict__ Wd,
        float* __restrict__ recon, const int* scal,
        const int* __restrict__ sel_idx, const unsigned* __restrict__ sel_bits, double* acc) {
    int row = blockIdx.x, t = threadIdx.x;
    unsigned t24 = (unsigned)scal[S_T24M];
    int selcnt = min(scal[S_SELCNT], SEL_CAP);
    __shared__ int lj[2048];
    __shared__ float lv[2048];
    __shared__ int lcnt;
    __shared__ float sred[4];
    const int d0 = t * 4;
    float4 r;
    r.x = b_dec[d0]; r.y = b_dec[d0 + 1]; r.z = b_dec[d0 + 2]; r.w = b_dec[d0 + 3];
    float4 xv = *(const float4*)(x + (size_t)row * ND + d0);
    const float* arow = acts + (size_t)row * NS;
    const int bnds[5] = {0, 2048, 6144, 14336, NS};
    for (int g = 0; g < 4; g++) {
        for (int c0 = bnds[g]; c0 < bnds[g + 1]; c0 += 2048) {
            __syncthreads();
            if (t == 0) lcnt = 0;
            __syncthreads();
            #pragma unroll
            for (int u = 0; u < 8; u++) {
                int c = c0 + u * 256 + t;
                float v = arow[c];
                unsigned bits = __float_as_uint(v);
                unsigned pre = bits >> 8;
                bool keep = pre > t24;
                if (!keep && pre == t24) {
                    int flat = row * NS + c;
                    for (int e = 0; e < selcnt; e++)
                        if (sel_idx[e] == flat) { keep = true; break; }
                }
                if (keep) { int p = atomicAdd(&lcnt, 1); lj[p] = c; lv[p] = v; }
            }
            __syncthreads();
            int n = lcnt;
            for (int e = 0; e < n; e++) {
                float a_ = lv[e];
                float4 w = *(const float4*)(Wd + (size_t)lj[e] * ND + d0);
                r.x = fmaf(a_, w.x, r.x);
                r.y = fmaf(a_, w.y, r.y);
                r.z = fmaf(a_, w.z, r.z);
                r.w = fmaf(a_, w.w, r.w);
            }
        }
        float dx = r.x - xv.x, dy = r.y - xv.y, dz = r.z - xv.z, dw = r.w - xv.w;
        float ss = dx * dx + dy * dy + dz * dz + dw * dw;
        float tot = blk_reduce(ss, sred);
        if (t == 0) atomicAdd(&acc[A_L2_0 + g], (double)tot);
    }
    float* orow = recon + (size_t)row * ND + d0;   // region misaligned -> scalar stores
    orow[0] = r.x; orow[1] = r.y; orow[2] = r.z; orow[3] = r.w;
}

// aux: recon_aux per row (sparse over dead cols above minval), accumulate squared error vs residual
__global__ __launch_bounds__(256) void k_aux(const float* __restrict__ acts,
        const unsigned char* __restrict__ dead, const float* __restrict__ x,
        const float* __restrict__ recon, const float* __restrict__ Wd,
        const int* scal, double* acc) {
    int row = blockIdx.x, t = threadIdx.x;
    float minval = __uint_as_float((unsigned)scal[S_MINBITS]);
    __shared__ int lj[2048];
    __shared__ float lv[2048];
    __shared__ int lcnt;
    __shared__ float sred[4];
    float4 r = {0.f, 0.f, 0.f, 0.f};
    const float* arow = acts + (size_t)row * NS;
    const int d0 = t * 4;
    for (int c0 = 0; c0 < NS; c0 += 2048) {
        __syncthreads();
        if (t == 0) lcnt = 0;
        __syncthreads();
        #pragma unroll
        for (int u = 0; u < 8; u++) {
            int c = c0 + u * 256 + t;
            float v = arow[c];
            if (dead[c] && v > minval) {
                int p = atomicAdd(&lcnt, 1);
                lj[p] = c; lv[p] = v - minval;
            }
        }
        __syncthreads();
        int n = lcnt;
        for (int e = 0; e < n; e++) {
            float a_ = lv[e];
            float4 w = *(const float4*)(Wd + (size_t)lj[e] * ND + d0);
            r.x = fmaf(a_, w.x, r.x);
            r.y = fmaf(a_, w.y, r.y);
            r.z = fmaf(a_, w.z, r.z);
            r.w = fmaf(a_, w.w, r.w);
        }
    }
    const float* xr = x + (size_t)row * ND + d0;
    const float* rr = recon + (size_t)row * ND + d0;
    float dx = r.x - (xr[0] - rr[0]);
    float dy = r.y - (xr[1] - rr[1]);
    float dz = r.z - (xr[2] - rr[2]);
    float dw = r.w - (xr[3] - rr[3]);
    float ss = dx * dx + dy * dy + dz * dz + dw * dw;
    float tot = blk_reduce(ss, sred);
    if (t == 0) atomicAdd(&acc[A_AUX], (double)tot);
}

// in-place top-k zeroing over d_out acts region (handles the +5-float misalignment by peeling) + L1/L0
__global__ __launch_bounds__(256) void k_topk_write(float* __restrict__ out, const int* scal, double* acc, int* scalw) {
    unsigned t24 = (unsigned)scal[S_T24M];
    float l1 = 0.f;
    int cnt = 0;
    const long long vstart = 8, nvec = 15728639;   // [8, 62914564) as float4
    long long stride = (long long)gridDim.x * blockDim.x;
    for (long long i = (long long)blockIdx.x * blockDim.x + threadIdx.x; i < nvec; i += stride) {
        float4* p = (float4*)(out + vstart) + i;
        float4 v = *p;
        #define PROC(F) { unsigned b = __float_as_uint(v.F); if ((b >> 8) > t24) { l1 += v.F; cnt++; } else v.F = 0.f; }
        PROC(x) PROC(y) PROC(z) PROC(w)
        #undef PROC
        *p = v;
    }
    if (blockIdx.x == 0 && threadIdx.x == 0) {
        const long long head[4] = {5, 6, 7, 62914564LL};
        for (int q = 0; q < 4; q++) {
            float v = out[head[q]];
            unsigned b = __float_as_uint(v);
            if ((b >> 8) > t24) { l1 += v; cnt++; } else out[head[q]] = 0.f;
        }
    }
    int t = threadIdx.x;
    #pragma unroll
    for (int o = 32; o > 0; o >>= 1) { l1 += __shfl_down(l1, o, 64); cnt += __shfl_down(cnt, o, 64); }
    __shared__ float s1[4];
    __shared__ int s2[4];
    if ((t & 63) == 0) { s1[t >> 6] = l1; s2[t >> 6] = cnt; }
    __syncthreads();
    if (t == 0) {
        atomicAdd(&acc[A_L1], (double)(s1[0] + s1[1] + s1[2] + s1[3]));
        atomicAdd(&scalw[S_L0], s2[0] + s2[1] + s2[2] + s2[3]);
    }
}

// rewrite the selected boundary-bin entries (zeroed by k_topk_write) + their L1/L0 contribution
__global__ __launch_bounds__(256) void k_selwrite(float* __restrict__ acts, const int* __restrict__ sel_idx,
        const unsigned* __restrict__ sel_bits, int* scal, double* acc) {
    int t = threadIdx.x;
    int n = min(scal[S_SELCNT], SEL_CAP);
    float l1 = 0.f;
    for (int e = t; e < n; e += 256) {
        float v = __uint_as_float(sel_bits[e]);
        acts[sel_idx[e]] = v;
        l1 += v;
    }
    #pragma unroll
    for (int o = 32; o > 0; o >>= 1) l1 += __shfl_down(l1, o, 64);
    __shared__ float s1[4];
    if ((t & 63) == 0) s1[t >> 6] = l1;
    __syncthreads();
    if (t == 0) {
        atomicAdd(&acc[A_L1], (double)(s1[0] + s1[1] + s1[2] + s1[3]));
        atomicAdd(&scal[S_L0], n);
    }
}

__global__ void k_final(float* out, const int* scal, const double* acc) {
    if (threadIdx.x == 0 && blockIdx.x == 0) {
        double ml2 = (acc[0] + acc[1] + acc[2] + acc[3]) * 0.25 / ((double)NB * ND);
        double l1 = 1e-3 * acc[A_L1] / (double)NB;
        double aux = (scal[S_NDEAD] > 0) ? (1e-2 * acc[A_AUX] / ((double)NB * ND)) : 0.0;
        out[0] = (float)(ml2 + l1 + aux);
        out[1] = (float)ml2;
        out[2] = (float)l1;
        out[3] = (float)aux;
        out[4] = (float)scal[S_L0] / (float)NB;
    }
}

// ---------------- launch ----------------
extern "C" void kernel_launch(void* const* d_in, const int* in_sizes, int n_in,
                              void* d_out, int out_size, void* d_ws, size_t ws_size,
                              hipStream_t stream) {
    const float* x     = (const float*)d_in[0];
    const float* b_dec = (const float*)d_in[1];
    const float* b_enc = (const float*)d_in[2];
    const float* W_enc = (const float*)d_in[3];
    const float* W_dec = (const float*)d_in[4];
    const int*   nbna  = (const int*)d_in[5];

    float* out = (float*)d_out;
    float* acts  = out + 5;                         // [NB, NS] (misaligned region)
    float* recon = out + 5 + (size_t)NB * NS;       // [NB, ND]

    char* ws = (char*)d_ws;
    int*    scal = (int*)(ws + OFF_SCAL);
    double* acc  = (double*)(ws + OFF_ACC);
    int*    h1m  = (int*)(ws + OFF_H1M);
    int*    h1a  = (int*)(ws + OFF_H1A);
    int*    h2m  = (int*)(ws + OFF_H2M);
    int*    h2a  = (int*)(ws + OFF_H2A);
    unsigned char* dead = (unsigned char*)(ws + OFF_DEAD);
    int*      sel_idx  = (int*)(ws + OFF_SEL_IDX);
    unsigned* sel_bits = (unsigned*)(ws + OFF_SEL_BITS);
    unsigned* cmb = (unsigned*)(ws + OFF_CMB);
    int*      cmi = (int*)(ws + OFF_CMI);
    unsigned* cab = (unsigned*)(ws + OFF_CAB);
    int*      cai = (int*)(ws + OFF_CAI);

    k_init<<<64, 256, 0, stream>>>((int*)d_ws);
    k_dead<<<60, 256, 0, stream>>>(nbna, dead, scal);
    k_enc_gemm<<<dim3(NS / GBN, NB / GBM), 256, 0, stream>>>(x, b_dec, b_enc, W_enc, acts);
    k_hist1<<<1024, 256, 0, stream>>>(acts, dead, h1m, h1a);
    k_scan<<<1, 256, 0, stream>>>(h1m, scal, 0);
    k_scan<<<1, 256, 0, stream>>>(h1a, scal, 1);
    k_hist2<<<NB, 256, 0, stream>>>(acts, dead, scal, h2m, h2a);
    k_scan<<<1, 256, 0, stream>>>(h2m, scal, 2);
    k_scan<<<1, 256, 0, stream>>>(h2a, scal, 3);
    k_collect<<<NB, 256, 0, stream>>>(acts, dead, scal, cmb, cmi, cab, cai);
    k_resolve<<<1, 256, 0, stream>>>(cmb, cmi, cab, scal, sel_idx, sel_bits);
    k_decode<<<NB, 256, 0, stream>>>(acts, x, b_dec, W_dec, recon, scal, sel_idx, sel_bits, acc);
    k_aux<<<NB, 256, 0, stream>>>(acts, dead, x, recon, W_dec, scal, acc);
    k_topk_write<<<4096, 256, 0, stream>>>(out, scal, acc, scal);
    k_selwrite<<<1, 256, 0, stream>>>(acts, sel_idx, sel_bits, scal, acc);
    k_final<<<1, 64, 0, stream>>>(out, scal, acc);
}

// Round 3
// 3754.750 us; speedup vs baseline: 1.2577x; 1.2577x over previous
//
#include <hip/hip_runtime.h>

// ---------------- problem constants ----------------
#define NB 2048
#define ND 1024
#define NS 30720
#define K_MAIN 131072LL           // TOP_K * B
#define K_AUX  2097152LL          // TOP_K * AUX_K_MULT * B
#define BAND_CAP 16384
#define SEL_CAP  8192
#define CANDA_CAP 65536
#define EPS_BAND 1e-3f            // covers worst-case |fp32 - fp64| per element (~2e-4) with 5x margin

// ---------------- ws layout (bytes) ----------------
#define OFF_SCAL 0                // int[64]
#define OFF_ACC  256              // double[8]
#define OFF_H1M  512              // int[4096]
#define OFF_H1A  16896
#define OFF_H2M  33280
#define OFF_H2A  49664
#define OFF_ZERO_END 66048        // zeroed every launch
#define OFF_DEAD 66048            // 30720 bytes
#define OFF_SEL_IDX 98304         // int[SEL_CAP]
#define OFF_SEL_BITS 131072       // uint[SEL_CAP]
#define OFF_BANDI 163840          // int[BAND_CAP]
#define OFF_BANDV 229376          // double[BAND_CAP]
#define OFF_CAB  360448           // uint[CANDA_CAP]  (ends 622592)

// scal indices
#define S_NDEAD 0
#define S_B1M 1
#define S_REM1M 2
#define S_B1A 3
#define S_REM1A 4
#define S_T24M 5
#define S_BLO 6
#define S_BHI 7
#define S_T24A 8
#define S_JA 9
#define S_NHI 10
#define S_BANDC 11
#define S_CCA 12
#define S_SELCNT 13
#define S_L0 14
#define S_MINBITS 15

// acc indices
#define A_L2_0 0
#define A_L1 4
#define A_AUX 5

// ---------------- helpers ----------------
__device__ __forceinline__ float blk_reduce(float v, float* sred) {
    int t = threadIdx.x;
    #pragma unroll
    for (int o = 32; o > 0; o >>= 1) v += __shfl_down(v, o, 64);
    __syncthreads();
    if ((t & 63) == 0) sred[t >> 6] = v;
    __syncthreads();
    return sred[0] + sred[1] + sred[2] + sred[3];
}

// ---------------- kernels ----------------
__global__ void k_init(int* w) {
    int n = OFF_ZERO_END / 4;
    for (int i = blockIdx.x * blockDim.x + threadIdx.x; i < n; i += gridDim.x * blockDim.x)
        w[i] = 0;
}

__global__ void k_dead(const int* __restrict__ nbna, unsigned char* __restrict__ dead, int* scal) {
    int stride = gridDim.x * blockDim.x;
    int cnt = 0;
    for (int i = blockIdx.x * blockDim.x + threadIdx.x; i < NS; i += stride) {
        bool d = nbna[i] >= 20;
        dead[i] = d ? 1 : 0;
        cnt += d ? 1 : 0;
    }
    #pragma unroll
    for (int o = 32; o > 0; o >>= 1) cnt += __shfl_down(cnt, o, 64);
    if ((threadIdx.x & 63) == 0 && cnt) atomicAdd(&scal[S_NDEAD], cnt);
}

// encoder GEMM, fp32: acts = relu((x - b_dec) @ W_enc + b_enc)
// fragment mapping tx*4 / 64+tx*4 -> LDS reads are <=2-way conflict (free, m136)
#define GBM 128
#define GBN 128
#define GBK 8
__global__ __launch_bounds__(256) void k_enc_gemm(const float* __restrict__ x,
        const float* __restrict__ b_dec, const float* __restrict__ b_enc,
        const float* __restrict__ W, float* __restrict__ acts) {
    __shared__ float As[GBK][GBM];
    __shared__ float Bs[GBK][GBN];
    const int t = threadIdx.x;
    const int tx = t & 15, ty = t >> 4;
    const int m0 = blockIdx.y * GBM, n0 = blockIdx.x * GBN;
    const int am = t >> 1, ak = (t & 1) * 4;
    const int bk = t >> 5, bnq = (t & 31) * 4;

    float acc[8][8];
    #pragma unroll
    for (int i = 0; i < 8; i++)
        #pragma unroll
        for (int j = 0; j < 8; j++) acc[i][j] = 0.f;

    for (int k0 = 0; k0 < ND; k0 += GBK) {
        float4 av = *(const float4*)(x + (size_t)(m0 + am) * ND + k0 + ak);
        float4 bd = *(const float4*)(b_dec + k0 + ak);
        As[ak + 0][am] = av.x - bd.x;
        As[ak + 1][am] = av.y - bd.y;
        As[ak + 2][am] = av.z - bd.z;
        As[ak + 3][am] = av.w - bd.w;
        *(float4*)&Bs[bk][bnq] = *(const float4*)(W + (size_t)(k0 + bk) * NS + n0 + bnq);
        __syncthreads();
        #pragma unroll
        for (int kk = 0; kk < GBK; kk++) {
            float a[8], b[8];
            *(float4*)&a[0] = *(const float4*)&As[kk][ty * 4];
            *(float4*)&a[4] = *(const float4*)&As[kk][64 + ty * 4];
            *(float4*)&b[0] = *(const float4*)&Bs[kk][tx * 4];
            *(float4*)&b[4] = *(const float4*)&Bs[kk][64 + tx * 4];
            #pragma unroll
            for (int i = 0; i < 8; i++)
                #pragma unroll
                for (int j = 0; j < 8; j++)
                    acc[i][j] = fmaf(a[i], b[j], acc[i][j]);
        }
        __syncthreads();
    }
    float be[8];
    #pragma unroll
    for (int j = 0; j < 4; j++) {
        be[j]     = b_enc[n0 + tx * 4 + j];
        be[4 + j] = b_enc[n0 + 64 + tx * 4 + j];
    }
    #pragma unroll
    for (int i = 0; i < 8; i++) {
        int row = m0 + ((i < 4) ? (ty * 4 + i) : (64 + ty * 4 + i - 4));
        float* orow = acts + (size_t)row * NS + n0;   // region misaligned -> scalar stores
        #pragma unroll
        for (int j = 0; j < 4; j++) {
            orow[tx * 4 + j]      = fmaxf(acc[i][j] + be[j], 0.f);
            orow[64 + tx * 4 + j] = fmaxf(acc[i][4 + j] + be[4 + j], 0.f);
        }
    }
}

// fused coarse histograms: main (all) + aux (dead cols only); bins = bits >> 20
__global__ __launch_bounds__(256) void k_hist1(const float* __restrict__ acts,
        const unsigned char* __restrict__ dead, int* h1m, int* h1a) {
    __shared__ int hm[4096], ha[4096];
    int t = threadIdx.x;
    for (int i = t; i < 4096; i += 256) { hm[i] = 0; ha[i] = 0; }
    __syncthreads();
    for (int row = blockIdx.x; row < NB; row += gridDim.x) {
        const float* pr = acts + (size_t)row * NS;
        for (int c = t; c < NS; c += 256) {
            unsigned bits = __float_as_uint(pr[c]);
            bool isz = (bits == 0u);
            bool dd = dead[c] != 0;
            unsigned long long mz = __ballot(isz);
            unsigned long long mza = __ballot(isz && dd);
            if ((t & 63) == 0) {
                int nz = __popcll(mz);
                if (nz) atomicAdd(&hm[0], nz);
                int nza = __popcll(mza);
                if (nza) atomicAdd(&ha[0], nza);
            }
            if (!isz) {
                atomicAdd(&hm[bits >> 20], 1);
                if (dd) atomicAdd(&ha[bits >> 20], 1);
            }
        }
    }
    __syncthreads();
    for (int i = t; i < 4096; i += 256) {
        if (hm[i]) atomicAdd(&h1m[i], hm[i]);
        if (ha[i]) atomicAdd(&h1a[i], ha[i]);
    }
}

// suffix-scan over a 4096-bin histogram; finds bin containing rank k (from top)
// mode 0: main coarse; 1: aux coarse; 2: main fine (-> t24m + band bounds); 3: aux fine
__global__ void k_scan(const int* __restrict__ hist, int* scal, int mode) {
    __shared__ long long csum[256];
    __shared__ long long totsh;
    int t = threadIdx.x;
    int base = t * 16;
    int h[16];
    long long loc = 0;
    #pragma unroll
    for (int i = 0; i < 16; i++) { h[i] = hist[base + i]; loc += h[i]; }
    csum[t] = loc;
    __syncthreads();
    if (t == 0) {
        long long run = 0;
        for (int c = 255; c >= 0; c--) { long long tmp = csum[c]; csum[c] = run; run += tmp; }
        totsh = run;
    }
    __syncthreads();
    long long k;
    if (mode == 0) k = K_MAIN;
    else if (mode == 1) k = K_AUX;
    else if (mode == 2) k = (long long)scal[S_REM1M];
    else {
        if (scal[S_B1A] < 0) { if (t == 0) { scal[S_T24A] = -1; scal[S_MINBITS] = 0; } return; }
        k = (long long)scal[S_REM1A];
    }
    if (mode == 1 && k > totsh) { if (t == 0) scal[S_B1A] = -1; return; }
    long long cum = csum[t];
    int fb = -1; long long rem = 0;
    for (int i = 15; i >= 0; i--) {
        long long ca = cum;
        cum += h[i];
        if (ca < k && k <= cum) { fb = base + i; rem = k - ca; }
    }
    if (fb >= 0) {
        if (mode == 0)      { scal[S_B1M] = fb; scal[S_REM1M] = (int)rem; }
        else if (mode == 1) { scal[S_B1A] = fb; scal[S_REM1A] = (int)rem; }
        else if (mode == 2) {
            int t24 = (scal[S_B1M] << 12) | fb;
            scal[S_T24M] = t24;
            float center = __uint_as_float((((unsigned)t24) << 8) | 128u);
            float lo = center - EPS_BAND;
            if (lo < 0.f) lo = 0.f;
            scal[S_BLO] = (int)__float_as_uint(lo);
            scal[S_BHI] = (int)__float_as_uint(center + EPS_BAND);
        }
        else { scal[S_T24A] = (scal[S_B1A] << 12) | fb; scal[S_JA] = (int)rem; }
    }
}

// fine histograms inside the selected coarse bins
__global__ __launch_bounds__(256) void k_hist2(const float* __restrict__ acts,
        const unsigned char* __restrict__ dead, const int* scal, int* h2m, int* h2a) {
    int b1m = scal[S_B1M], b1a = scal[S_B1A];
    int row = blockIdx.x, t = threadIdx.x;
    const float* pr = acts + (size_t)row * NS;
    for (int c = t; c < NS; c += 256) {
        unsigned bits = __float_as_uint(pr[c]);
        int hi = (int)(bits >> 20);
        if (hi == b1m) atomicAdd(&h2m[(bits >> 8) & 0xFFF], 1);
        if (b1a >= 0 && hi == b1a && dead[c]) atomicAdd(&h2a[(bits >> 8) & 0xFFF], 1);
    }
}

// single pass: exact count above band (n_hi), band-member collection, aux candidates
__global__ __launch_bounds__(256) void k_collect(const float* __restrict__ acts,
        const unsigned char* __restrict__ dead, int* scal,
        int* bandi, unsigned* cab) {
    int row = blockIdx.x, t = threadIdx.x;
    unsigned blo = (unsigned)scal[S_BLO], bhi = (unsigned)scal[S_BHI];
    int t24a = scal[S_T24A];
    const float* pr = acts + (size_t)row * NS;
    int cnt = 0;
    for (int c = t; c < NS; c += 256) {
        unsigned bits = __float_as_uint(pr[c]);
        if (bits > bhi) cnt++;
        else if (bits >= blo) {
            int p = atomicAdd(&scal[S_BANDC], 1);
            if (p < BAND_CAP) bandi[p] = row * NS + c;
        }
        if (t24a >= 0 && (bits >> 8) == (unsigned)t24a && dead[c]) {
            int p = atomicAdd(&scal[S_CCA], 1);
            if (p < CANDA_CAP) cab[p] = bits;
        }
    }
    #pragma unroll
    for (int o = 32; o > 0; o >>= 1) cnt += __shfl_down(cnt, o, 64);
    __shared__ int s2[4];
    if ((t & 63) == 0) s2[t >> 6] = cnt;
    __syncthreads();
    if (t == 0) {
        int tot = s2[0] + s2[1] + s2[2] + s2[3];
        if (tot) atomicAdd(&scal[S_NHI], tot);
    }
}

// aux threshold value from boundary-fine-bin candidates (fp32 exact; value-only, no tie info needed)
__global__ __launch_bounds__(256) void k_resolve(const unsigned* __restrict__ cab, int* scal) {
    __shared__ int h[256];
    int t = threadIdx.x;
    h[t] = 0;
    __syncthreads();
    int t24a = scal[S_T24A];
    if (t24a < 0) { if (t == 0) scal[S_MINBITS] = 0; return; }
    int cnt = min(scal[S_CCA], CANDA_CAP);
    int ja = scal[S_JA];
    for (int e = t; e < cnt; e += 256) atomicAdd(&h[cab[e] & 0xFF], 1);
    __syncthreads();
    if (t == 0) {
        long long cum = 0; int L = 0;
        for (int b = 255; b >= 0; b--) {
            long long ca = cum; cum += h[b];
            if (ca < ja && ja <= cum) { L = b; break; }
        }
        scal[S_MINBITS] = (int)((((unsigned)t24a) << 8) | (unsigned)L);
    }
}

// fp64 recompute of band elements (one block per element, strided)
__global__ __launch_bounds__(256) void k_band_re(const float* __restrict__ x,
        const float* __restrict__ b_dec, const float* __restrict__ b_enc,
        const float* __restrict__ W, const int* scal,
        const int* __restrict__ bandi, double* __restrict__ bandv) {
    int n = min(scal[S_BANDC], BAND_CAP);
    int t = threadIdx.x;
    __shared__ double sd[4];
    for (int e = blockIdx.x; e < n; e += gridDim.x) {
        int idx = bandi[e];
        int r = idx / NS, c = idx - r * NS;
        double s = 0.0;
        #pragma unroll
        for (int j = 0; j < 4; j++) {
            int d = t + j * 256;
            s += ((double)x[(size_t)r * ND + d] - (double)b_dec[d]) * (double)W[(size_t)d * NS + c];
        }
        #pragma unroll
        for (int o = 32; o > 0; o >>= 1) s += __shfl_down(s, o, 64);
        if ((t & 63) == 0) sd[t >> 6] = s;
        __syncthreads();
        if (t == 0) {
            double v = sd[0] + sd[1] + sd[2] + sd[3] + (double)b_enc[c];
            bandv[e] = fmax(v, 0.0);
        }
        __syncthreads();
    }
}

// exact selection within band: rank by (v64 desc, idx asc); keep rank < need = K - n_hi
__global__ __launch_bounds__(256) void k_band_sel(int* scal,
        const int* __restrict__ bandi, const double* __restrict__ bandv,
        int* sel_idx, unsigned* sel_bits) {
    int n = min(scal[S_BANDC], BAND_CAP);
    int need = (int)(K_MAIN - (long long)scal[S_NHI]);
    if (need < 0) need = 0;
    if (need > n) need = n;
    int t = threadIdx.x;
    for (int e = t; e < n; e += 256) {
        double v = bandv[e];
        int idx = bandi[e];
        int rank = 0;
        for (int j = 0; j < n; j++) {
            double vj = bandv[j];
            rank += (vj > v || (vj == v && bandi[j] < idx)) ? 1 : 0;
        }
        if (rank < need) {
            int p = atomicAdd(&scal[S_SELCNT], 1);
            if (p < SEL_CAP) { sel_idx[p] = idx; sel_bits[p] = __float_as_uint((float)v); }
        }
    }
}

// hierarchical sparse decode: one block per row; membership = bits > bhi OR selected band element
__global__ __launch_bounds__(256) void k_decode(const float* __restrict__ acts,
        const float* __restrict__ x, const float* __restrict__ b_dec, const float* __restrict__ Wd,
        float* __restrict__ recon, const int* scal,
        const int* __restrict__ sel_idx, double* acc) {
    int row = blockIdx.x, t = threadIdx.x;
    unsigned blo = (unsigned)scal[S_BLO], bhi = (unsigned)scal[S_BHI];
    int selcnt = min(scal[S_SELCNT], SEL_CAP);
    __shared__ int lj[2048];
    __shared__ float lv[2048];
    __shared__ int lcnt;
    __shared__ float sred[4];
    const int d0 = t * 4;
    float4 r;
    r.x = b_dec[d0]; r.y = b_dec[d0 + 1]; r.z = b_dec[d0 + 2]; r.w = b_dec[d0 + 3];
    float4 xv = *(const float4*)(x + (size_t)row * ND + d0);
    const float* arow = acts + (size_t)row * NS;
    const int bnds[5] = {0, 2048, 6144, 14336, NS};
    for (int g = 0; g < 4; g++) {
        for (int c0 = bnds[g]; c0 < bnds[g + 1]; c0 += 2048) {
            __syncthreads();
            if (t == 0) lcnt = 0;
            __syncthreads();
            #pragma unroll
            for (int u = 0; u < 8; u++) {
                int c = c0 + u * 256 + t;
                float v = arow[c];
                unsigned bits = __float_as_uint(v);
                bool keep = bits > bhi;
                if (!keep && bits >= blo) {
                    int flat = row * NS + c;
                    for (int e = 0; e < selcnt; e++)
                        if (sel_idx[e] == flat) { keep = true; break; }
                }
                if (keep) { int p = atomicAdd(&lcnt, 1); lj[p] = c; lv[p] = v; }
            }
            __syncthreads();
            int n = lcnt;
            for (int e = 0; e < n; e++) {
                float a_ = lv[e];
                float4 w = *(const float4*)(Wd + (size_t)lj[e] * ND + d0);
                r.x = fmaf(a_, w.x, r.x);
                r.y = fmaf(a_, w.y, r.y);
                r.z = fmaf(a_, w.z, r.z);
                r.w = fmaf(a_, w.w, r.w);
            }
        }
        float dx = r.x - xv.x, dy = r.y - xv.y, dz = r.z - xv.z, dw = r.w - xv.w;
        float ss = dx * dx + dy * dy + dz * dz + dw * dw;
        float tot = blk_reduce(ss, sred);
        if (t == 0) atomicAdd(&acc[A_L2_0 + g], (double)tot);
    }
    float* orow = recon + (size_t)row * ND + d0;   // region misaligned -> scalar stores
    orow[0] = r.x; orow[1] = r.y; orow[2] = r.z; orow[3] = r.w;
}

// aux: recon_aux per row (sparse over dead cols above minval), accumulate squared error vs residual
__global__ __launch_bounds__(256) void k_aux(const float* __restrict__ acts,
        const unsigned char* __restrict__ dead, const float* __restrict__ x,
        const float* __restrict__ recon, const float* __restrict__ Wd,
        const int* scal, double* acc) {
    int row = blockIdx.x, t = threadIdx.x;
    float minval = __uint_as_float((unsigned)scal[S_MINBITS]);
    __shared__ int lj[2048];
    __shared__ float lv[2048];
    __shared__ int lcnt;
    __shared__ float sred[4];
    float4 r = {0.f, 0.f, 0.f, 0.f};
    const float* arow = acts + (size_t)row * NS;
    const int d0 = t * 4;
    for (int c0 = 0; c0 < NS; c0 += 2048) {
        __syncthreads();
        if (t == 0) lcnt = 0;
        __syncthreads();
        #pragma unroll
        for (int u = 0; u < 8; u++) {
            int c = c0 + u * 256 + t;
            float v = arow[c];
            if (dead[c] && v > minval) {
                int p = atomicAdd(&lcnt, 1);
                lj[p] = c; lv[p] = v - minval;
            }
        }
        __syncthreads();
        int n = lcnt;
        for (int e = 0; e < n; e++) {
            float a_ = lv[e];
            float4 w = *(const float4*)(Wd + (size_t)lj[e] * ND + d0);
            r.x = fmaf(a_, w.x, r.x);
            r.y = fmaf(a_, w.y, r.y);
            r.z = fmaf(a_, w.z, r.z);
            r.w = fmaf(a_, w.w, r.w);
        }
    }
    const float* xr = x + (size_t)row * ND + d0;
    const float* rr = recon + (size_t)row * ND + d0;
    float dx = r.x - (xr[0] - rr[0]);
    float dy = r.y - (xr[1] - rr[1]);
    float dz = r.z - (xr[2] - rr[2]);
    float dw = r.w - (xr[3] - rr[3]);
    float ss = dx * dx + dy * dy + dz * dz + dw * dw;
    float tot = blk_reduce(ss, sred);
    if (t == 0) atomicAdd(&acc[A_AUX], (double)tot);
}

// in-place top-k zeroing over d_out acts region (strict bits > bhi) + L1/L0 for definite members
__global__ __launch_bounds__(256) void k_topk_write(float* __restrict__ out, const int* scal, double* acc, int* scalw) {
    unsigned bhi = (unsigned)scal[S_BHI];
    float l1 = 0.f;
    int cnt = 0;
    const long long vstart = 8, nvec = 15728639;   // [8, 62914564) as float4
    long long stride = (long long)gridDim.x * blockDim.x;
    for (long long i = (long long)blockIdx.x * blockDim.x + threadIdx.x; i < nvec; i += stride) {
        float4* p = (float4*)(out + vstart) + i;
        float4 v = *p;
        #define PROC(F) { unsigned b = __float_as_uint(v.F); if (b > bhi) { l1 += v.F; cnt++; } else v.F = 0.f; }
        PROC(x) PROC(y) PROC(z) PROC(w)
        #undef PROC
        *p = v;
    }
    if (blockIdx.x == 0 && threadIdx.x == 0) {
        const long long head[4] = {5, 6, 7, 62914564LL};
        for (int q = 0; q < 4; q++) {
            float v = out[head[q]];
            unsigned b = __float_as_uint(v);
            if (b > bhi) { l1 += v; cnt++; } else out[head[q]] = 0.f;
        }
    }
    int t = threadIdx.x;
    #pragma unroll
    for (int o = 32; o > 0; o >>= 1) { l1 += __shfl_down(l1, o, 64); cnt += __shfl_down(cnt, o, 64); }
    __shared__ float s1[4];
    __shared__ int s2[4];
    if ((t & 63) == 0) { s1[t >> 6] = l1; s2[t >> 6] = cnt; }
    __syncthreads();
    if (t == 0) {
        atomicAdd(&acc[A_L1], (double)(s1[0] + s1[1] + s1[2] + s1[3]));
        atomicAdd(&scalw[S_L0], s2[0] + s2[1] + s2[2] + s2[3]);
    }
}

// rewrite the selected band entries (zeroed by k_topk_write) + their L1/L0 contribution
__global__ __launch_bounds__(256) void k_selwrite(float* __restrict__ acts, const int* __restrict__ sel_idx,
        const unsigned* __restrict__ sel_bits, int* scal, double* acc) {
    int t = threadIdx.x;
    int n = min(scal[S_SELCNT], SEL_CAP);
    float l1 = 0.f;
    for (int e = t; e < n; e += 256) {
        float v = __uint_as_float(sel_bits[e]);
        acts[sel_idx[e]] = v;
        l1 += v;
    }
    #pragma unroll
    for (int o = 32; o > 0; o >>= 1) l1 += __shfl_down(l1, o, 64);
    __shared__ float s1[4];
    if ((t & 63) == 0) s1[t >> 6] = l1;
    __syncthreads();
    if (t == 0) {
        atomicAdd(&acc[A_L1], (double)(s1[0] + s1[1] + s1[2] + s1[3]));
        atomicAdd(&scal[S_L0], n);
    }
}

__global__ void k_final(float* out, const int* scal, const double* acc) {
    if (threadIdx.x == 0 && blockIdx.x == 0) {
        double ml2 = (acc[0] + acc[1] + acc[2] + acc[3]) * 0.25 / ((double)NB * ND);
        double l1 = 1e-3 * acc[A_L1] / (double)NB;
        double aux = (scal[S_NDEAD] > 0) ? (1e-2 * acc[A_AUX] / ((double)NB * ND)) : 0.0;
        out[0] = (float)(ml2 + l1 + aux);
        out[1] = (float)ml2;
        out[2] = (float)l1;
        out[3] = (float)aux;
        out[4] = (float)scal[S_L0] / (float)NB;
    }
}

// ---------------- launch ----------------
extern "C" void kernel_launch(void* const* d_in, const int* in_sizes, int n_in,
                              void* d_out, int out_size, void* d_ws, size_t ws_size,
                              hipStream_t stream) {
    const float* x     = (const float*)d_in[0];
    const float* b_dec = (const float*)d_in[1];
    const float* b_enc = (const float*)d_in[2];
    const float* W_enc = (const float*)d_in[3];
    const float* W_dec = (const float*)d_in[4];
    const int*   nbna  = (const int*)d_in[5];

    float* out = (float*)d_out;
    float* acts  = out + 5;                         // [NB, NS] (misaligned region)
    float* recon = out + 5 + (size_t)NB * NS;       // [NB, ND]

    char* ws = (char*)d_ws;
    int*    scal = (int*)(ws + OFF_SCAL);
    double* acc  = (double*)(ws + OFF_ACC);
    int*    h1m  = (int*)(ws + OFF_H1M);
    int*    h1a  = (int*)(ws + OFF_H1A);
    int*    h2m  = (int*)(ws + OFF_H2M);
    int*    h2a  = (int*)(ws + OFF_H2A);
    unsigned char* dead = (unsigned char*)(ws + OFF_DEAD);
    int*      sel_idx  = (int*)(ws + OFF_SEL_IDX);
    unsigned* sel_bits = (unsigned*)(ws + OFF_SEL_BITS);
    int*      bandi = (int*)(ws + OFF_BANDI);
    double*   bandv = (double*)(ws + OFF_BANDV);
    unsigned* cab   = (unsigned*)(ws + OFF_CAB);

    k_init<<<64, 256, 0, stream>>>((int*)d_ws);
    k_dead<<<60, 256, 0, stream>>>(nbna, dead, scal);
    k_enc_gemm<<<dim3(NS / GBN, NB / GBM), 256, 0, stream>>>(x, b_dec, b_enc, W_enc, acts);
    k_hist1<<<1024, 256, 0, stream>>>(acts, dead, h1m, h1a);
    k_scan<<<1, 256, 0, stream>>>(h1m, scal, 0);
    k_scan<<<1, 256, 0, stream>>>(h1a, scal, 1);
    k_hist2<<<NB, 256, 0, stream>>>(acts, dead, scal, h2m, h2a);
    k_scan<<<1, 256, 0, stream>>>(h2m, scal, 2);
    k_scan<<<1, 256, 0, stream>>>(h2a, scal, 3);
    k_collect<<<NB, 256, 0, stream>>>(acts, dead, scal, bandi, cab);
    k_resolve<<<1, 256, 0, stream>>>(cab, scal);
    k_band_re<<<512, 256, 0, stream>>>(x, b_dec, b_enc, W_enc, scal, bandi, bandv);
    k_band_sel<<<1, 256, 0, stream>>>(scal, bandi, bandv, sel_idx, sel_bits);
    k_decode<<<NB, 256, 0, stream>>>(acts, x, b_dec, W_dec, recon, scal, sel_idx, acc);
    k_aux<<<NB, 256, 0, stream>>>(acts, dead, x, recon, W_dec, scal, acc);
    k_topk_write<<<4096, 256, 0, stream>>>(out, scal, acc, scal);
    k_selwrite<<<1, 256, 0, stream>>>(acts, sel_idx, sel_bits, scal, acc);
    k_final<<<1, 64, 0, stream>>>(out, scal, acc);
}

// Round 4
// 2774.899 us; speedup vs baseline: 1.7018x; 1.3531x over previous
//
#include <hip/hip_runtime.h>

// ---------------- problem constants ----------------
#define NB 2048
#define ND 1024
#define NS 30720
#define K_MAIN 131072LL           // TOP_K * B
#define K_AUX  2097152LL          // TOP_K * AUX_K_MULT * B
#define BAND_CAP 16384
#define SEL_CAP  8192
#define CANDA_CAP 65536
#define EPS_BAND 1e-3f            // covers worst-case |approx - fp64| per element with big margin

// ---------------- ws layout (bytes) ----------------
#define OFF_SCAL 0                // int[64]
#define OFF_ACC  256              // double[8]
#define OFF_H1M  512              // int[4096]
#define OFF_H1A  16896
#define OFF_H2M  33280
#define OFF_H2A  49664
#define OFF_ZERO_END 66048        // zeroed every launch
#define OFF_DEAD 66048            // 30720 bytes
#define OFF_SEL_IDX 98304         // int[SEL_CAP]
#define OFF_SEL_BITS 131072       // uint[SEL_CAP]
#define OFF_BANDI 163840          // int[BAND_CAP]
#define OFF_BANDV 229376          // double[BAND_CAP]
#define OFF_CAB  360448           // uint[CANDA_CAP]  (ends 622592)
// split-bf16 planes for the MFMA GEMM
#define OFF_AH   1048576ULL                         // [2048][1024] bf16 = 4 MB
#define OFF_AL   (OFF_AH + 2048ULL*1024*2)
#define OFF_WHT  (OFF_AL + 2048ULL*1024*2)          // [30720][1024] bf16 = 60 MB (transposed)
#define OFF_WLT  (OFF_WHT + 30720ULL*1024*2)
#define WS_NEED  (OFF_WLT + 30720ULL*1024*2)        // ~129 MB

// scal indices
#define S_NDEAD 0
#define S_B1M 1
#define S_REM1M 2
#define S_B1A 3
#define S_REM1A 4
#define S_T24M 5
#define S_BLO 6
#define S_BHI 7
#define S_T24A 8
#define S_JA 9
#define S_NHI 10
#define S_BANDC 11
#define S_CCA 12
#define S_SELCNT 13
#define S_L0 14
#define S_MINBITS 15

// acc indices
#define A_L2_0 0
#define A_L1 4
#define A_AUX 5

typedef __attribute__((ext_vector_type(8))) short bf16x8;
typedef __attribute__((ext_vector_type(4))) float f32x4;

// ---------------- helpers ----------------
__device__ __forceinline__ float blk_reduce(float v, float* sred) {
    int t = threadIdx.x;
    #pragma unroll
    for (int o = 32; o > 0; o >>= 1) v += __shfl_down(v, o, 64);
    __syncthreads();
    if ((t & 63) == 0) sred[t >> 6] = v;
    __syncthreads();
    return sred[0] + sred[1] + sred[2] + sred[3];
}

__device__ __forceinline__ unsigned short f2bf(float f) {
    unsigned u = __float_as_uint(f);
    unsigned r = (u + 0x7FFFu + ((u >> 16) & 1u)) >> 16;   // RNE
    return (unsigned short)r;
}
__device__ __forceinline__ float bf2f(unsigned short h) {
    return __uint_as_float(((unsigned)h) << 16);
}

#define GLD16(gp, lp) __builtin_amdgcn_global_load_lds( \
    (const __attribute__((address_space(1))) unsigned int*)(gp), \
    (__attribute__((address_space(3))) unsigned int*)(lp), 16, 0, 0)

// ---------------- kernels ----------------
__global__ void k_init(int* w) {
    int n = OFF_ZERO_END / 4;
    for (int i = blockIdx.x * blockDim.x + threadIdx.x; i < n; i += gridDim.x * blockDim.x)
        w[i] = 0;
}

__global__ void k_dead(const int* __restrict__ nbna, unsigned char* __restrict__ dead, int* scal) {
    int stride = gridDim.x * blockDim.x;
    int cnt = 0;
    for (int i = blockIdx.x * blockDim.x + threadIdx.x; i < NS; i += stride) {
        bool d = nbna[i] >= 20;
        dead[i] = d ? 1 : 0;
        cnt += d ? 1 : 0;
    }
    #pragma unroll
    for (int o = 32; o > 0; o >>= 1) cnt += __shfl_down(cnt, o, 64);
    if ((threadIdx.x & 63) == 0 && cnt) atomicAdd(&scal[S_NDEAD], cnt);
}

// split (x - b_dec) into bf16 hi/lo planes, [M][K]
__global__ void k_prep_a(const float* __restrict__ x, const float* __restrict__ b_dec,
                         unsigned short* __restrict__ Ahg, unsigned short* __restrict__ Alg) {
    int stride = gridDim.x * blockDim.x;
    for (int i = blockIdx.x * blockDim.x + threadIdx.x; i < NB * ND; i += stride) {
        float v = x[i] - b_dec[i & (ND - 1)];
        unsigned short h = f2bf(v);
        unsigned short l = f2bf(v - bf2f(h));
        Ahg[i] = h; Alg[i] = l;
    }
}

// transpose + split W_enc [K][N] fp32 -> WhT/WlT [N][K] bf16 (32x32 tiles via LDS)
__global__ __launch_bounds__(256) void k_prep_w(const float* __restrict__ W,
        unsigned short* __restrict__ WhT, unsigned short* __restrict__ WlT) {
    __shared__ float tile[32][33];
    int n0 = blockIdx.x * 32, k0 = blockIdx.y * 32;
    int t = threadIdx.x;
    int c = t & 31, r = t >> 5;          // r in 0..7
    #pragma unroll
    for (int it = 0; it < 4; it++)
        tile[r + it * 8][c] = W[(size_t)(k0 + r + it * 8) * NS + n0 + c];
    __syncthreads();
    int kl = t & 31, nl = t >> 5;
    #pragma unroll
    for (int it = 0; it < 4; it++) {
        float v = tile[kl][nl + it * 8];
        unsigned short h = f2bf(v);
        unsigned short l = f2bf(v - bf2f(h));
        size_t o = (size_t)(n0 + nl + it * 8) * ND + k0 + kl;
        WhT[o] = h; WlT[o] = l;
    }
}

// split-bf16 MFMA encoder GEMM: acts = relu(A@W + b_enc), A=Ah+Al, W=Wh+Wl (3 products)
// 128x128 tile, BK=32, 4 waves, 64x64/wave as 4x4 mfma_f32_16x16x32_bf16 tiles
__global__ __launch_bounds__(256) void k_enc_mfma(
        const unsigned short* __restrict__ Ahg, const unsigned short* __restrict__ Alg,
        const unsigned short* __restrict__ WhT, const unsigned short* __restrict__ WlT,
        const float* __restrict__ b_enc, float* __restrict__ acts) {
    __shared__ unsigned short Ah[128 * 32], Al[128 * 32], Bh[128 * 32], Bl[128 * 32];
    const int t = threadIdx.x;
    const int lane = t & 63, w = t >> 6;
    const int wm = w >> 1, wn = w & 1;
    const int m0 = blockIdx.y * 128, n0 = blockIdx.x * 128;
    const int ln15 = lane & 15, q = lane >> 4;

    f32x4 acc[4][4];
    #pragma unroll
    for (int i = 0; i < 4; i++)
        #pragma unroll
        for (int j = 0; j < 4; j++) acc[i][j] = (f32x4){0.f, 0.f, 0.f, 0.f};

    // per-wave staging plane: 0->Ah, 1->Al, 2->Bh, 3->Bl
    const unsigned short* gbase;
    unsigned short* lbase;
    if (w == 0)      { gbase = Ahg + (size_t)m0 * ND; lbase = Ah; }
    else if (w == 1) { gbase = Alg + (size_t)m0 * ND; lbase = Al; }
    else if (w == 2) { gbase = WhT + (size_t)n0 * ND; lbase = Bh; }
    else             { gbase = WlT + (size_t)n0 * ND; lbase = Bl; }
    const unsigned short* glane = gbase + (size_t)(lane >> 2) * ND + (lane & 3) * 8;

    for (int k0 = 0; k0 < ND; k0 += 32) {
        __syncthreads();
        #pragma unroll
        for (int ch = 0; ch < 8; ch++)
            GLD16(glane + (size_t)ch * 16 * ND + k0, lbase + ch * 512);
        __syncthreads();

        bf16x8 ah[4], al[4];
        #pragma unroll
        for (int i = 0; i < 4; i++) {
            int r = wm * 64 + i * 16 + ln15;
            ah[i] = *(const bf16x8*)&Ah[r * 32 + q * 8];
            al[i] = *(const bf16x8*)&Al[r * 32 + q * 8];
        }
        #pragma unroll
        for (int j = 0; j < 4; j++) {
            int rb = wn * 64 + j * 16 + ln15;
            bf16x8 bhj = *(const bf16x8*)&Bh[rb * 32 + q * 8];
            bf16x8 blj = *(const bf16x8*)&Bl[rb * 32 + q * 8];
            #pragma unroll
            for (int i = 0; i < 4; i++) {
                acc[i][j] = __builtin_amdgcn_mfma_f32_16x16x32_bf16(ah[i], bhj, acc[i][j], 0, 0, 0);
                acc[i][j] = __builtin_amdgcn_mfma_f32_16x16x32_bf16(ah[i], blj, acc[i][j], 0, 0, 0);
                acc[i][j] = __builtin_amdgcn_mfma_f32_16x16x32_bf16(al[i], bhj, acc[i][j], 0, 0, 0);
            }
        }
    }
    // epilogue: C/D layout col=lane&15, row=quad*4+reg; acts region misaligned -> scalar stores
    #pragma unroll
    for (int j = 0; j < 4; j++) {
        int n = n0 + wn * 64 + j * 16 + ln15;
        float be = b_enc[n];
        #pragma unroll
        for (int i = 0; i < 4; i++) {
            int mrow = m0 + wm * 64 + i * 16 + q * 4;
            #pragma unroll
            for (int rg = 0; rg < 4; rg++)
                acts[(size_t)(mrow + rg) * NS + n] = fmaxf(acc[i][j][rg] + be, 0.f);
        }
    }
}

// fallback fp32 encoder GEMM (used when ws too small for bf16 planes)
#define GBM 128
#define GBN 128
#define GBK 8
__global__ __launch_bounds__(256) void k_enc_gemm(const float* __restrict__ x,
        const float* __restrict__ b_dec, const float* __restrict__ b_enc,
        const float* __restrict__ W, float* __restrict__ acts) {
    __shared__ float As[GBK][GBM];
    __shared__ float Bs[GBK][GBN];
    const int t = threadIdx.x;
    const int tx = t & 15, ty = t >> 4;
    const int m0 = blockIdx.y * GBM, n0 = blockIdx.x * GBN;
    const int am = t >> 1, ak = (t & 1) * 4;
    const int bk = t >> 5, bnq = (t & 31) * 4;
    float acc[8][8];
    #pragma unroll
    for (int i = 0; i < 8; i++)
        #pragma unroll
        for (int j = 0; j < 8; j++) acc[i][j] = 0.f;
    for (int k0 = 0; k0 < ND; k0 += GBK) {
        float4 av = *(const float4*)(x + (size_t)(m0 + am) * ND + k0 + ak);
        float4 bd = *(const float4*)(b_dec + k0 + ak);
        As[ak + 0][am] = av.x - bd.x;
        As[ak + 1][am] = av.y - bd.y;
        As[ak + 2][am] = av.z - bd.z;
        As[ak + 3][am] = av.w - bd.w;
        *(float4*)&Bs[bk][bnq] = *(const float4*)(W + (size_t)(k0 + bk) * NS + n0 + bnq);
        __syncthreads();
        #pragma unroll
        for (int kk = 0; kk < GBK; kk++) {
            float a[8], b[8];
            *(float4*)&a[0] = *(const float4*)&As[kk][ty * 4];
            *(float4*)&a[4] = *(const float4*)&As[kk][64 + ty * 4];
            *(float4*)&b[0] = *(const float4*)&Bs[kk][tx * 4];
            *(float4*)&b[4] = *(const float4*)&Bs[kk][64 + tx * 4];
            #pragma unroll
            for (int i = 0; i < 8; i++)
                #pragma unroll
                for (int j = 0; j < 8; j++)
                    acc[i][j] = fmaf(a[i], b[j], acc[i][j]);
        }
        __syncthreads();
    }
    float be[8];
    #pragma unroll
    for (int j = 0; j < 4; j++) {
        be[j]     = b_enc[n0 + tx * 4 + j];
        be[4 + j] = b_enc[n0 + 64 + tx * 4 + j];
    }
    #pragma unroll
    for (int i = 0; i < 8; i++) {
        int row = m0 + ((i < 4) ? (ty * 4 + i) : (64 + ty * 4 + i - 4));
        float* orow = acts + (size_t)row * NS + n0;
        #pragma unroll
        for (int j = 0; j < 4; j++) {
            orow[tx * 4 + j]      = fmaxf(acc[i][j] + be[j], 0.f);
            orow[64 + tx * 4 + j] = fmaxf(acc[i][4 + j] + be[4 + j], 0.f);
        }
    }
}

// fused coarse histograms: main (all) + aux (dead cols only); bins = bits >> 20
__global__ __launch_bounds__(256) void k_hist1(const float* __restrict__ acts,
        const unsigned char* __restrict__ dead, int* h1m, int* h1a) {
    __shared__ int hm[4096], ha[4096];
    int t = threadIdx.x;
    for (int i = t; i < 4096; i += 256) { hm[i] = 0; ha[i] = 0; }
    __syncthreads();
    for (int row = blockIdx.x; row < NB; row += gridDim.x) {
        const float* pr = acts + (size_t)row * NS;
        for (int c = t; c < NS; c += 256) {
            unsigned bits = __float_as_uint(pr[c]);
            bool isz = (bits == 0u);
            bool dd = dead[c] != 0;
            unsigned long long mz = __ballot(isz);
            unsigned long long mza = __ballot(isz && dd);
            if ((t & 63) == 0) {
                int nz = __popcll(mz);
                if (nz) atomicAdd(&hm[0], nz);
                int nza = __popcll(mza);
                if (nza) atomicAdd(&ha[0], nza);
            }
            if (!isz) {
                atomicAdd(&hm[bits >> 20], 1);
                if (dd) atomicAdd(&ha[bits >> 20], 1);
            }
        }
    }
    __syncthreads();
    for (int i = t; i < 4096; i += 256) {
        if (hm[i]) atomicAdd(&h1m[i], hm[i]);
        if (ha[i]) atomicAdd(&h1a[i], ha[i]);
    }
}

// suffix-scan over a 4096-bin histogram; finds bin containing rank k (from top)
__global__ void k_scan(const int* __restrict__ hist, int* scal, int mode) {
    __shared__ long long csum[256];
    __shared__ long long totsh;
    int t = threadIdx.x;
    int base = t * 16;
    int h[16];
    long long loc = 0;
    #pragma unroll
    for (int i = 0; i < 16; i++) { h[i] = hist[base + i]; loc += h[i]; }
    csum[t] = loc;
    __syncthreads();
    if (t == 0) {
        long long run = 0;
        for (int c = 255; c >= 0; c--) { long long tmp = csum[c]; csum[c] = run; run += tmp; }
        totsh = run;
    }
    __syncthreads();
    long long k;
    if (mode == 0) k = K_MAIN;
    else if (mode == 1) k = K_AUX;
    else if (mode == 2) k = (long long)scal[S_REM1M];
    else {
        if (scal[S_B1A] < 0) { if (t == 0) { scal[S_T24A] = -1; scal[S_MINBITS] = 0; } return; }
        k = (long long)scal[S_REM1A];
    }
    if (mode == 1 && k > totsh) { if (t == 0) scal[S_B1A] = -1; return; }
    long long cum = csum[t];
    int fb = -1; long long rem = 0;
    for (int i = 15; i >= 0; i--) {
        long long ca = cum;
        cum += h[i];
        if (ca < k && k <= cum) { fb = base + i; rem = k - ca; }
    }
    if (fb >= 0) {
        if (mode == 0)      { scal[S_B1M] = fb; scal[S_REM1M] = (int)rem; }
        else if (mode == 1) { scal[S_B1A] = fb; scal[S_REM1A] = (int)rem; }
        else if (mode == 2) {
            int t24 = (scal[S_B1M] << 12) | fb;
            scal[S_T24M] = t24;
            float center = __uint_as_float((((unsigned)t24) << 8) | 128u);
            float lo = center - EPS_BAND;
            if (lo < 0.f) lo = 0.f;
            scal[S_BLO] = (int)__float_as_uint(lo);
            scal[S_BHI] = (int)__float_as_uint(center + EPS_BAND);
        }
        else { scal[S_T24A] = (scal[S_B1A] << 12) | fb; scal[S_JA] = (int)rem; }
    }
}

// fine histograms inside the selected coarse bins
__global__ __launch_bounds__(256) void k_hist2(const float* __restrict__ acts,
        const unsigned char* __restrict__ dead, const int* scal, int* h2m, int* h2a) {
    int b1m = scal[S_B1M], b1a = scal[S_B1A];
    int row = blockIdx.x, t = threadIdx.x;
    const float* pr = acts + (size_t)row * NS;
    for (int c = t; c < NS; c += 256) {
        unsigned bits = __float_as_uint(pr[c]);
        int hi = (int)(bits >> 20);
        if (hi == b1m) atomicAdd(&h2m[(bits >> 8) & 0xFFF], 1);
        if (b1a >= 0 && hi == b1a && dead[c]) atomicAdd(&h2a[(bits >> 8) & 0xFFF], 1);
    }
}

// single pass: exact count above band (n_hi), band-member collection, aux candidates
__global__ __launch_bounds__(256) void k_collect(const float* __restrict__ acts,
        const unsigned char* __restrict__ dead, int* scal,
        int* bandi, unsigned* cab) {
    int row = blockIdx.x, t = threadIdx.x;
    unsigned blo = (unsigned)scal[S_BLO], bhi = (unsigned)scal[S_BHI];
    int t24a = scal[S_T24A];
    const float* pr = acts + (size_t)row * NS;
    int cnt = 0;
    for (int c = t; c < NS; c += 256) {
        unsigned bits = __float_as_uint(pr[c]);
        if (bits > bhi) cnt++;
        else if (bits >= blo) {
            int p = atomicAdd(&scal[S_BANDC], 1);
            if (p < BAND_CAP) bandi[p] = row * NS + c;
        }
        if (t24a >= 0 && (bits >> 8) == (unsigned)t24a && dead[c]) {
            int p = atomicAdd(&scal[S_CCA], 1);
            if (p < CANDA_CAP) cab[p] = bits;
        }
    }
    #pragma unroll
    for (int o = 32; o > 0; o >>= 1) cnt += __shfl_down(cnt, o, 64);
    __shared__ int s2[4];
    if ((t & 63) == 0) s2[t >> 6] = cnt;
    __syncthreads();
    if (t == 0) {
        int tot = s2[0] + s2[1] + s2[2] + s2[3];
        if (tot) atomicAdd(&scal[S_NHI], tot);
    }
}

// aux threshold value from boundary-fine-bin candidates
__global__ __launch_bounds__(256) void k_resolve(const unsigned* __restrict__ cab, int* scal) {
    __shared__ int h[256];
    int t = threadIdx.x;
    h[t] = 0;
    __syncthreads();
    int t24a = scal[S_T24A];
    if (t24a < 0) { if (t == 0) scal[S_MINBITS] = 0; return; }
    int cnt = min(scal[S_CCA], CANDA_CAP);
    int ja = scal[S_JA];
    for (int e = t; e < cnt; e += 256) atomicAdd(&h[cab[e] & 0xFF], 1);
    __syncthreads();
    if (t == 0) {
        long long cum = 0; int L = 0;
        for (int b = 255; b >= 0; b--) {
            long long ca = cum; cum += h[b];
            if (ca < ja && ja <= cum) { L = b; break; }
        }
        scal[S_MINBITS] = (int)((((unsigned)t24a) << 8) | (unsigned)L);
    }
}

// fp64 recompute of band elements (exact vs reference)
__global__ __launch_bounds__(256) void k_band_re(const float* __restrict__ x,
        const float* __restrict__ b_dec, const float* __restrict__ b_enc,
        const float* __restrict__ W, const int* scal,
        const int* __restrict__ bandi, double* __restrict__ bandv) {
    int n = min(scal[S_BANDC], BAND_CAP);
    int t = threadIdx.x;
    __shared__ double sd[4];
    for (int e = blockIdx.x; e < n; e += gridDim.x) {
        int idx = bandi[e];
        int r = idx / NS, c = idx - r * NS;
        double s = 0.0;
        #pragma unroll
        for (int j = 0; j < 4; j++) {
            int d = t + j * 256;
            s += ((double)x[(size_t)r * ND + d] - (double)b_dec[d]) * (double)W[(size_t)d * NS + c];
        }
        #pragma unroll
        for (int o = 32; o > 0; o >>= 1) s += __shfl_down(s, o, 64);
        if ((t & 63) == 0) sd[t >> 6] = s;
        __syncthreads();
        if (t == 0) {
            double v = sd[0] + sd[1] + sd[2] + sd[3] + (double)b_enc[c];
            bandv[e] = fmax(v, 0.0);
        }
        __syncthreads();
    }
}

// exact selection within band: rank by (v64 desc, idx asc); keep rank < need = K - n_hi
__global__ __launch_bounds__(256) void k_band_sel(int* scal,
        const int* __restrict__ bandi, const double* __restrict__ bandv,
        int* sel_idx, unsigned* sel_bits) {
    int n = min(scal[S_BANDC], BAND_CAP);
    int need = (int)(K_MAIN - (long long)scal[S_NHI]);
    if (need < 0) need = 0;
    if (need > n) need = n;
    int t = threadIdx.x;
    for (int e = t; e < n; e += 256) {
        double v = bandv[e];
        int idx = bandi[e];
        int rank = 0;
        for (int j = 0; j < n; j++) {
            double vj = bandv[j];
            rank += (vj > v || (vj == v && bandi[j] < idx)) ? 1 : 0;
        }
        if (rank < need) {
            int p = atomicAdd(&scal[S_SELCNT], 1);
            if (p < SEL_CAP) { sel_idx[p] = idx; sel_bits[p] = __float_as_uint((float)v); }
        }
    }
}

// hierarchical sparse decode: one block per row; membership = bits > bhi OR selected band element
__global__ __launch_bounds__(256) void k_decode(const float* __restrict__ acts,
        const float* __restrict__ x, const float* __restrict__ b_dec, const float* __restrict__ Wd,
        float* __restrict__ recon, const int* scal,
        const int* __restrict__ sel_idx, double* acc) {
    int row = blockIdx.x, t = threadIdx.x;
    unsigned blo = (unsigned)scal[S_BLO], bhi = (unsigned)scal[S_BHI];
    int selcnt = min(scal[S_SELCNT], SEL_CAP);
    __shared__ int lj[2048];
    __shared__ float lv[2048];
    __shared__ int lcnt;
    __shared__ float sred[4];
    const int d0 = t * 4;
    float4 r;
    r.x = b_dec[d0]; r.y = b_dec[d0 + 1]; r.z = b_dec[d0 + 2]; r.w = b_dec[d0 + 3];
    float4 xv = *(const float4*)(x + (size_t)row * ND + d0);
    const float* arow = acts + (size_t)row * NS;
    const int bnds[5] = {0, 2048, 6144, 14336, NS};
    for (int g = 0; g < 4; g++) {
        for (int c0 = bnds[g]; c0 < bnds[g + 1]; c0 += 2048) {
            __syncthreads();
            if (t == 0) lcnt = 0;
            __syncthreads();
            #pragma unroll
            for (int u = 0; u < 8; u++) {
                int c = c0 + u * 256 + t;
                float v = arow[c];
                unsigned bits = __float_as_uint(v);
                bool keep = bits > bhi;
                if (!keep && bits >= blo) {
                    int flat = row * NS + c;
                    for (int e = 0; e < selcnt; e++)
                        if (sel_idx[e] == flat) { keep = true; break; }
                }
                if (keep) { int p = atomicAdd(&lcnt, 1); lj[p] = c; lv[p] = v; }
            }
            __syncthreads();
            int n = lcnt;
            for (int e = 0; e < n; e++) {
                float a_ = lv[e];
                float4 w = *(const float4*)(Wd + (size_t)lj[e] * ND + d0);
                r.x = fmaf(a_, w.x, r.x);
                r.y = fmaf(a_, w.y, r.y);
                r.z = fmaf(a_, w.z, r.z);
                r.w = fmaf(a_, w.w, r.w);
            }
        }
        float dx = r.x - xv.x, dy = r.y - xv.y, dz = r.z - xv.z, dw = r.w - xv.w;
        float ss = dx * dx + dy * dy + dz * dz + dw * dw;
        float tot = blk_reduce(ss, sred);
        if (t == 0) atomicAdd(&acc[A_L2_0 + g], (double)tot);
    }
    float* orow = recon + (size_t)row * ND + d0;   // region misaligned -> scalar stores
    orow[0] = r.x; orow[1] = r.y; orow[2] = r.z; orow[3] = r.w;
}

// aux: recon_aux per row (sparse over dead cols above minval), accumulate squared error vs residual
__global__ __launch_bounds__(256) void k_aux(const float* __restrict__ acts,
        const unsigned char* __restrict__ dead, const float* __restrict__ x,
        const float* __restrict__ recon, const float* __restrict__ Wd,
        const int* scal, double* acc) {
    int row = blockIdx.x, t = threadIdx.x;
    float minval = __uint_as_float((unsigned)scal[S_MINBITS]);
    __shared__ int lj[2048];
    __shared__ float lv[2048];
    __shared__ int lcnt;
    __shared__ float sred[4];
    float4 r = {0.f, 0.f, 0.f, 0.f};
    const float* arow = acts + (size_t)row * NS;
    const int d0 = t * 4;
    for (int c0 = 0; c0 < NS; c0 += 2048) {
        __syncthreads();
        if (t == 0) lcnt = 0;
        __syncthreads();
        #pragma unroll
        for (int u = 0; u < 8; u++) {
            int c = c0 + u * 256 + t;
            float v = arow[c];
            if (dead[c] && v > minval) {
                int p = atomicAdd(&lcnt, 1);
                lj[p] = c; lv[p] = v - minval;
            }
        }
        __syncthreads();
        int n = lcnt;
        for (int e = 0; e < n; e++) {
            float a_ = lv[e];
            float4 w = *(const float4*)(Wd + (size_t)lj[e] * ND + d0);
            r.x = fmaf(a_, w.x, r.x);
            r.y = fmaf(a_, w.y, r.y);
            r.z = fmaf(a_, w.z, r.z);
            r.w = fmaf(a_, w.w, r.w);
        }
    }
    const float* xr = x + (size_t)row * ND + d0;
    const float* rr = recon + (size_t)row * ND + d0;
    float dx = r.x - (xr[0] - rr[0]);
    float dy = r.y - (xr[1] - rr[1]);
    float dz = r.z - (xr[2] - rr[2]);
    float dw = r.w - (xr[3] - rr[3]);
    float ss = dx * dx + dy * dy + dz * dz + dw * dw;
    float tot = blk_reduce(ss, sred);
    if (t == 0) atomicAdd(&acc[A_AUX], (double)tot);
}

// in-place top-k zeroing over d_out acts region (strict bits > bhi) + L1/L0 for definite members
__global__ __launch_bounds__(256) void k_topk_write(float* __restrict__ out, const int* scal, double* acc, int* scalw) {
    unsigned bhi = (unsigned)scal[S_BHI];
    float l1 = 0.f;
    int cnt = 0;
    const long long vstart = 8, nvec = 15728639;   // [8, 62914564) as float4
    long long stride = (long long)gridDim.x * blockDim.x;
    for (long long i = (long long)blockIdx.x * blockDim.x + threadIdx.x; i < nvec; i += stride) {
        float4* p = (float4*)(out + vstart) + i;
        float4 v = *p;
        #define PROC(F) { unsigned b = __float_as_uint(v.F); if (b > bhi) { l1 += v.F; cnt++; } else v.F = 0.f; }
        PROC(x) PROC(y) PROC(z) PROC(w)
        #undef PROC
        *p = v;
    }
    if (blockIdx.x == 0 && threadIdx.x == 0) {
        const long long head[4] = {5, 6, 7, 62914564LL};
        for (int q = 0; q < 4; q++) {
            float v = out[head[q]];
            unsigned b = __float_as_uint(v);
            if (b > bhi) { l1 += v; cnt++; } else out[head[q]] = 0.f;
        }
    }
    int t = threadIdx.x;
    #pragma unroll
    for (int o = 32; o > 0; o >>= 1) { l1 += __shfl_down(l1, o, 64); cnt += __shfl_down(cnt, o, 64); }
    __shared__ float s1[4];
    __shared__ int s2[4];
    if ((t & 63) == 0) { s1[t >> 6] = l1; s2[t >> 6] = cnt; }
    __syncthreads();
    if (t == 0) {
        atomicAdd(&acc[A_L1], (double)(s1[0] + s1[1] + s1[2] + s1[3]));
        atomicAdd(&scalw[S_L0], s2[0] + s2[1] + s2[2] + s2[3]);
    }
}

// rewrite the selected band entries (zeroed by k_topk_write) + their L1/L0 contribution
__global__ __launch_bounds__(256) void k_selwrite(float* __restrict__ acts, const int* __restrict__ sel_idx,
        const unsigned* __restrict__ sel_bits, int* scal, double* acc) {
    int t = threadIdx.x;
    int n = min(scal[S_SELCNT], SEL_CAP);
    float l1 = 0.f;
    for (int e = t; e < n; e += 256) {
        float v = __uint_as_float(sel_bits[e]);
        acts[sel_idx[e]] = v;
        l1 += v;
    }
    #pragma unroll
    for (int o = 32; o > 0; o >>= 1) l1 += __shfl_down(l1, o, 64);
    __shared__ float s1[4];
    if ((t & 63) == 0) s1[t >> 6] = l1;
    __syncthreads();
    if (t == 0) {
        atomicAdd(&acc[A_L1], (double)(s1[0] + s1[1] + s1[2] + s1[3]));
        atomicAdd(&scal[S_L0], n);
    }
}

__global__ void k_final(float* out, const int* scal, const double* acc) {
    if (threadIdx.x == 0 && blockIdx.x == 0) {
        double ml2 = (acc[0] + acc[1] + acc[2] + acc[3]) * 0.25 / ((double)NB * ND);
        double l1 = 1e-3 * acc[A_L1] / (double)NB;
        double aux = (scal[S_NDEAD] > 0) ? (1e-2 * acc[A_AUX] / ((double)NB * ND)) : 0.0;
        out[0] = (float)(ml2 + l1 + aux);
        out[1] = (float)ml2;
        out[2] = (float)l1;
        out[3] = (float)aux;
        out[4] = (float)scal[S_L0] / (float)NB;
    }
}

// ---------------- launch ----------------
extern "C" void kernel_launch(void* const* d_in, const int* in_sizes, int n_in,
                              void* d_out, int out_size, void* d_ws, size_t ws_size,
                              hipStream_t stream) {
    const float* x     = (const float*)d_in[0];
    const float* b_dec = (const float*)d_in[1];
    const float* b_enc = (const float*)d_in[2];
    const float* W_enc = (const float*)d_in[3];
    const float* W_dec = (const float*)d_in[4];
    const int*   nbna  = (const int*)d_in[5];

    float* out = (float*)d_out;
    float* acts  = out + 5;                         // [NB, NS] (misaligned region)
    float* recon = out + 5 + (size_t)NB * NS;       // [NB, ND]

    char* ws = (char*)d_ws;
    int*    scal = (int*)(ws + OFF_SCAL);
    double* acc  = (double*)(ws + OFF_ACC);
    int*    h1m  = (int*)(ws + OFF_H1M);
    int*    h1a  = (int*)(ws + OFF_H1A);
    int*    h2m  = (int*)(ws + OFF_H2M);
    int*    h2a  = (int*)(ws + OFF_H2A);
    unsigned char* dead = (unsigned char*)(ws + OFF_DEAD);
    int*      sel_idx  = (int*)(ws + OFF_SEL_IDX);
    unsigned* sel_bits = (unsigned*)(ws + OFF_SEL_BITS);
    int*      bandi = (int*)(ws + OFF_BANDI);
    double*   bandv = (double*)(ws + OFF_BANDV);
    unsigned* cab   = (unsigned*)(ws + OFF_CAB);
    unsigned short* Ahg = (unsigned short*)(ws + OFF_AH);
    unsigned short* Alg = (unsigned short*)(ws + OFF_AL);
    unsigned short* WhT = (unsigned short*)(ws + OFF_WHT);
    unsigned short* WlT = (unsigned short*)(ws + OFF_WLT);

    const bool use_mfma = (ws_size >= WS_NEED);     // constant per process -> graph-stable

    k_init<<<64, 256, 0, stream>>>((int*)d_ws);
    k_dead<<<60, 256, 0, stream>>>(nbna, dead, scal);
    if (use_mfma) {
        k_prep_a<<<512, 256, 0, stream>>>(x, b_dec, Ahg, Alg);
        k_prep_w<<<dim3(NS / 32, ND / 32), 256, 0, stream>>>(W_enc, WhT, WlT);
        k_enc_mfma<<<dim3(NS / 128, NB / 128), 256, 0, stream>>>(Ahg, Alg, WhT, WlT, b_enc, acts);
    } else {
        k_enc_gemm<<<dim3(NS / GBN, NB / GBM), 256, 0, stream>>>(x, b_dec, b_enc, W_enc, acts);
    }
    k_hist1<<<1024, 256, 0, stream>>>(acts, dead, h1m, h1a);
    k_scan<<<1, 256, 0, stream>>>(h1m, scal, 0);
    k_scan<<<1, 256, 0, stream>>>(h1a, scal, 1);
    k_hist2<<<NB, 256, 0, stream>>>(acts, dead, scal, h2m, h2a);
    k_scan<<<1, 256, 0, stream>>>(h2m, scal, 2);
    k_scan<<<1, 256, 0, stream>>>(h2a, scal, 3);
    k_collect<<<NB, 256, 0, stream>>>(acts, dead, scal, bandi, cab);
    k_resolve<<<1, 256, 0, stream>>>(cab, scal);
    k_band_re<<<512, 256, 0, stream>>>(x, b_dec, b_enc, W_enc, scal, bandi, bandv);
    k_band_sel<<<1, 256, 0, stream>>>(scal, bandi, bandv, sel_idx, sel_bits);
    k_decode<<<NB, 256, 0, stream>>>(acts, x, b_dec, W_dec, recon, scal, sel_idx, acc);
    k_aux<<<NB, 256, 0, stream>>>(acts, dead, x, recon, W_dec, scal, acc);
    k_topk_write<<<4096, 256, 0, stream>>>(out, scal, acc, scal);
    k_selwrite<<<1, 256, 0, stream>>>(acts, sel_idx, sel_bits, scal, acc);
    k_final<<<1, 64, 0, stream>>>(out, scal, acc);
}

// Round 5
// 2158.193 us; speedup vs baseline: 2.1881x; 1.2858x over previous
//
#include <hip/hip_runtime.h>

// ---------------- problem constants ----------------
#define NB 2048
#define ND 1024
#define NS 30720
#define K_MAIN 131072LL           // TOP_K * B
#define K_AUX  2097152LL          // TOP_K * AUX_K_MULT * B
#define BAND_CAP 16384
#define SEL_CAP  8192
#define CANDA_CAP 65536
#define EPS_BAND 1e-3f            // covers worst-case |approx - fp64| per element with big margin
#define KSPLIT 4

// ---------------- ws layout (bytes) ----------------
#define OFF_SCAL 0                // int[64]
#define OFF_ACC  256              // double[8]
#define OFF_H1M  512              // int[4096]
#define OFF_H1A  16896
#define OFF_H2M  33280
#define OFF_H2A  49664
#define OFF_ZERO_END 66048        // zeroed every launch
#define OFF_DEAD 66048            // 30720 bytes
#define OFF_SEL_IDX 98304         // int[SEL_CAP]
#define OFF_SEL_BITS 131072       // uint[SEL_CAP]
#define OFF_BANDI 163840          // int[BAND_CAP]
#define OFF_BANDV 229376          // double[BAND_CAP]
#define OFF_CAB  360448           // uint[CANDA_CAP]  (ends 622592)
// aux GEMM per-split output planes: fp32 [KSPLIT][NB][ND] = 32 MB
#define OFF_RAUX 1048576ULL
// split-bf16 planes for the encoder MFMA GEMM
#define OFF_AH   (OFF_RAUX + (unsigned long long)KSPLIT * NB * ND * 4)   // 34603008
#define OFF_AL   (OFF_AH + 2048ULL*1024*2)
#define OFF_WHT  (OFF_AL + 2048ULL*1024*2)          // [30720][1024] bf16 = 60 MB (transposed)
#define OFF_WLT  (OFF_WHT + 30720ULL*1024*2)
#define WS_NEED_ENC (OFF_WLT + 30720ULL*1024*2)     // ~161 MB
// aux planes reuse the encoder-plane region (encoder GEMM is complete before aux pack)
#define OFF_AXB  OFF_AH                              // bf16 [NB][NS] = 126 MB
#define OFF_WDT  (OFF_AXB + 2048ULL*30720*2)         // bf16 [ND][NS] = 63 MB
#define WS_NEED_AUX (OFF_WDT + 1024ULL*30720*2)      // ~213 MB

// scal indices
#define S_NDEAD 0
#define S_B1M 1
#define S_REM1M 2
#define S_B1A 3
#define S_REM1A 4
#define S_T24M 5
#define S_BLO 6
#define S_BHI 7
#define S_T24A 8
#define S_JA 9
#define S_NHI 10
#define S_BANDC 11
#define S_CCA 12
#define S_SELCNT 13
#define S_L0 14
#define S_MINBITS 15

// acc indices
#define A_L2_0 0
#define A_L1 4
#define A_AUX 5

typedef __attribute__((ext_vector_type(8))) short bf16x8;
typedef __attribute__((ext_vector_type(4))) float f32x4;

// ---------------- helpers ----------------
__device__ __forceinline__ float blk_reduce(float v, float* sred) {
    int t = threadIdx.x;
    #pragma unroll
    for (int o = 32; o > 0; o >>= 1) v += __shfl_down(v, o, 64);
    __syncthreads();
    if ((t & 63) == 0) sred[t >> 6] = v;
    __syncthreads();
    return sred[0] + sred[1] + sred[2] + sred[3];
}

__device__ __forceinline__ unsigned short f2bf(float f) {
    unsigned u = __float_as_uint(f);
    unsigned r = (u + 0x7FFFu + ((u >> 16) & 1u)) >> 16;   // RNE
    return (unsigned short)r;
}
__device__ __forceinline__ float bf2f(unsigned short h) {
    return __uint_as_float(((unsigned)h) << 16);
}

#define GLD16(gp, lp) __builtin_amdgcn_global_load_lds( \
    (const __attribute__((address_space(1))) unsigned int*)(gp), \
    (__attribute__((address_space(3))) unsigned int*)(lp), 16, 0, 0)

// ---------------- kernels ----------------
__global__ void k_init(int* w) {
    int n = OFF_ZERO_END / 4;
    for (int i = blockIdx.x * blockDim.x + threadIdx.x; i < n; i += gridDim.x * blockDim.x)
        w[i] = 0;
}

__global__ void k_dead(const int* __restrict__ nbna, unsigned char* __restrict__ dead, int* scal) {
    int stride = gridDim.x * blockDim.x;
    int cnt = 0;
    for (int i = blockIdx.x * blockDim.x + threadIdx.x; i < NS; i += stride) {
        bool d = nbna[i] >= 20;
        dead[i] = d ? 1 : 0;
        cnt += d ? 1 : 0;
    }
    #pragma unroll
    for (int o = 32; o > 0; o >>= 1) cnt += __shfl_down(cnt, o, 64);
    if ((threadIdx.x & 63) == 0 && cnt) atomicAdd(&scal[S_NDEAD], cnt);
}

// split (x - b_dec) into bf16 hi/lo planes, [M][K]
__global__ void k_prep_a(const float* __restrict__ x, const float* __restrict__ b_dec,
                         unsigned short* __restrict__ Ahg, unsigned short* __restrict__ Alg) {
    int stride = gridDim.x * blockDim.x;
    for (int i = blockIdx.x * blockDim.x + threadIdx.x; i < NB * ND; i += stride) {
        float v = x[i] - b_dec[i & (ND - 1)];
        unsigned short h = f2bf(v);
        unsigned short l = f2bf(v - bf2f(h));
        Ahg[i] = h; Alg[i] = l;
    }
}

// transpose + split W_enc [K][N] fp32 -> WhT/WlT [N][K] bf16 (32x32 tiles via LDS)
__global__ __launch_bounds__(256) void k_prep_w(const float* __restrict__ W,
        unsigned short* __restrict__ WhT, unsigned short* __restrict__ WlT) {
    __shared__ float tile[32][33];
    int n0 = blockIdx.x * 32, k0 = blockIdx.y * 32;
    int t = threadIdx.x;
    int c = t & 31, r = t >> 5;          // r in 0..7
    #pragma unroll
    for (int it = 0; it < 4; it++)
        tile[r + it * 8][c] = W[(size_t)(k0 + r + it * 8) * NS + n0 + c];
    __syncthreads();
    int kl = t & 31, nl = t >> 5;
    #pragma unroll
    for (int it = 0; it < 4; it++) {
        float v = tile[kl][nl + it * 8];
        unsigned short h = f2bf(v);
        unsigned short l = f2bf(v - bf2f(h));
        size_t o = (size_t)(n0 + nl + it * 8) * ND + k0 + kl;
        WhT[o] = h; WlT[o] = l;
    }
}

// split-bf16 MFMA encoder GEMM: acts = relu(A@W + b_enc), A=Ah+Al, W=Wh+Wl (3 products)
__global__ __launch_bounds__(256) void k_enc_mfma(
        const unsigned short* __restrict__ Ahg, const unsigned short* __restrict__ Alg,
        const unsigned short* __restrict__ WhT, const unsigned short* __restrict__ WlT,
        const float* __restrict__ b_enc, float* __restrict__ acts) {
    __shared__ unsigned short Ah[128 * 32], Al[128 * 32], Bh[128 * 32], Bl[128 * 32];
    const int t = threadIdx.x;
    const int lane = t & 63, w = t >> 6;
    const int wm = w >> 1, wn = w & 1;
    const int m0 = blockIdx.y * 128, n0 = blockIdx.x * 128;
    const int ln15 = lane & 15, q = lane >> 4;

    f32x4 acc[4][4];
    #pragma unroll
    for (int i = 0; i < 4; i++)
        #pragma unroll
        for (int j = 0; j < 4; j++) acc[i][j] = (f32x4){0.f, 0.f, 0.f, 0.f};

    const unsigned short* gbase;
    unsigned short* lbase;
    if (w == 0)      { gbase = Ahg + (size_t)m0 * ND; lbase = Ah; }
    else if (w == 1) { gbase = Alg + (size_t)m0 * ND; lbase = Al; }
    else if (w == 2) { gbase = WhT + (size_t)n0 * ND; lbase = Bh; }
    else             { gbase = WlT + (size_t)n0 * ND; lbase = Bl; }
    const unsigned short* glane = gbase + (size_t)(lane >> 2) * ND + (lane & 3) * 8;

    for (int k0 = 0; k0 < ND; k0 += 32) {
        __syncthreads();
        #pragma unroll
        for (int ch = 0; ch < 8; ch++)
            GLD16(glane + (size_t)ch * 16 * ND + k0, lbase + ch * 512);
        __syncthreads();

        bf16x8 ah[4], al[4];
        #pragma unroll
        for (int i = 0; i < 4; i++) {
            int r = wm * 64 + i * 16 + ln15;
            ah[i] = *(const bf16x8*)&Ah[r * 32 + q * 8];
            al[i] = *(const bf16x8*)&Al[r * 32 + q * 8];
        }
        #pragma unroll
        for (int j = 0; j < 4; j++) {
            int rb = wn * 64 + j * 16 + ln15;
            bf16x8 bhj = *(const bf16x8*)&Bh[rb * 32 + q * 8];
            bf16x8 blj = *(const bf16x8*)&Bl[rb * 32 + q * 8];
            #pragma unroll
            for (int i = 0; i < 4; i++) {
                acc[i][j] = __builtin_amdgcn_mfma_f32_16x16x32_bf16(ah[i], bhj, acc[i][j], 0, 0, 0);
                acc[i][j] = __builtin_amdgcn_mfma_f32_16x16x32_bf16(ah[i], blj, acc[i][j], 0, 0, 0);
                acc[i][j] = __builtin_amdgcn_mfma_f32_16x16x32_bf16(al[i], bhj, acc[i][j], 0, 0, 0);
            }
        }
    }
    #pragma unroll
    for (int j = 0; j < 4; j++) {
        int n = n0 + wn * 64 + j * 16 + ln15;
        float be = b_enc[n];
        #pragma unroll
        for (int i = 0; i < 4; i++) {
            int mrow = m0 + wm * 64 + i * 16 + q * 4;
            #pragma unroll
            for (int rg = 0; rg < 4; rg++)
                acts[(size_t)(mrow + rg) * NS + n] = fmaxf(acc[i][j][rg] + be, 0.f);
        }
    }
}

// fallback fp32 encoder GEMM (used when ws too small for bf16 planes)
#define GBM 128
#define GBN 128
#define GBK 8
__global__ __launch_bounds__(256) void k_enc_gemm(const float* __restrict__ x,
        const float* __restrict__ b_dec, const float* __restrict__ b_enc,
        const float* __restrict__ W, float* __restrict__ acts) {
    __shared__ float As[GBK][GBM];
    __shared__ float Bs[GBK][GBN];
    const int t = threadIdx.x;
    const int tx = t & 15, ty = t >> 4;
    const int m0 = blockIdx.y * GBM, n0 = blockIdx.x * GBN;
    const int am = t >> 1, ak = (t & 1) * 4;
    const int bk = t >> 5, bnq = (t & 31) * 4;
    float acc[8][8];
    #pragma unroll
    for (int i = 0; i < 8; i++)
        #pragma unroll
        for (int j = 0; j < 8; j++) acc[i][j] = 0.f;
    for (int k0 = 0; k0 < ND; k0 += GBK) {
        float4 av = *(const float4*)(x + (size_t)(m0 + am) * ND + k0 + ak);
        float4 bd = *(const float4*)(b_dec + k0 + ak);
        As[ak + 0][am] = av.x - bd.x;
        As[ak + 1][am] = av.y - bd.y;
        As[ak + 2][am] = av.z - bd.z;
        As[ak + 3][am] = av.w - bd.w;
        *(float4*)&Bs[bk][bnq] = *(const float4*)(W + (size_t)(k0 + bk) * NS + n0 + bnq);
        __syncthreads();
        #pragma unroll
        for (int kk = 0; kk < GBK; kk++) {
            float a[8], b[8];
            *(float4*)&a[0] = *(const float4*)&As[kk][ty * 4];
            *(float4*)&a[4] = *(const float4*)&As[kk][64 + ty * 4];
            *(float4*)&b[0] = *(const float4*)&Bs[kk][tx * 4];
            *(float4*)&b[4] = *(const float4*)&Bs[kk][64 + tx * 4];
            #pragma unroll
            for (int i = 0; i < 8; i++)
                #pragma unroll
                for (int j = 0; j < 8; j++)
                    acc[i][j] = fmaf(a[i], b[j], acc[i][j]);
        }
        __syncthreads();
    }
    float be[8];
    #pragma unroll
    for (int j = 0; j < 4; j++) {
        be[j]     = b_enc[n0 + tx * 4 + j];
        be[4 + j] = b_enc[n0 + 64 + tx * 4 + j];
    }
    #pragma unroll
    for (int i = 0; i < 8; i++) {
        int row = m0 + ((i < 4) ? (ty * 4 + i) : (64 + ty * 4 + i - 4));
        float* orow = acts + (size_t)row * NS + n0;
        #pragma unroll
        for (int j = 0; j < 4; j++) {
            orow[tx * 4 + j]      = fmaxf(acc[i][j] + be[j], 0.f);
            orow[64 + tx * 4 + j] = fmaxf(acc[i][4 + j] + be[4 + j], 0.f);
        }
    }
}

// fused coarse histograms: main (all) + aux (dead cols only); bins = bits >> 20
__global__ __launch_bounds__(256) void k_hist1(const float* __restrict__ acts,
        const unsigned char* __restrict__ dead, int* h1m, int* h1a) {
    __shared__ int hm[4096], ha[4096];
    int t = threadIdx.x;
    for (int i = t; i < 4096; i += 256) { hm[i] = 0; ha[i] = 0; }
    __syncthreads();
    for (int row = blockIdx.x; row < NB; row += gridDim.x) {
        const float* pr = acts + (size_t)row * NS;
        for (int c = t; c < NS; c += 256) {
            unsigned bits = __float_as_uint(pr[c]);
            bool isz = (bits == 0u);
            bool dd = dead[c] != 0;
            unsigned long long mz = __ballot(isz);
            unsigned long long mza = __ballot(isz && dd);
            if ((t & 63) == 0) {
                int nz = __popcll(mz);
                if (nz) atomicAdd(&hm[0], nz);
                int nza = __popcll(mza);
                if (nza) atomicAdd(&ha[0], nza);
            }
            if (!isz) {
                atomicAdd(&hm[bits >> 20], 1);
                if (dd) atomicAdd(&ha[bits >> 20], 1);
            }
        }
    }
    __syncthreads();
    for (int i = t; i < 4096; i += 256) {
        if (hm[i]) atomicAdd(&h1m[i], hm[i]);
        if (ha[i]) atomicAdd(&h1a[i], ha[i]);
    }
}

// suffix-scan over a 4096-bin histogram; finds bin containing rank k (from top)
__global__ void k_scan(const int* __restrict__ hist, int* scal, int mode) {
    __shared__ long long csum[256];
    __shared__ long long totsh;
    int t = threadIdx.x;
    int base = t * 16;
    int h[16];
    long long loc = 0;
    #pragma unroll
    for (int i = 0; i < 16; i++) { h[i] = hist[base + i]; loc += h[i]; }
    csum[t] = loc;
    __syncthreads();
    if (t == 0) {
        long long run = 0;
        for (int c = 255; c >= 0; c--) { long long tmp = csum[c]; csum[c] = run; run += tmp; }
        totsh = run;
    }
    __syncthreads();
    long long k;
    if (mode == 0) k = K_MAIN;
    else if (mode == 1) k = K_AUX;
    else if (mode == 2) k = (long long)scal[S_REM1M];
    else {
        if (scal[S_B1A] < 0) { if (t == 0) { scal[S_T24A] = -1; scal[S_MINBITS] = 0; } return; }
        k = (long long)scal[S_REM1A];
    }
    if (mode == 1 && k > totsh) { if (t == 0) scal[S_B1A] = -1; return; }
    long long cum = csum[t];
    int fb = -1; long long rem = 0;
    for (int i = 15; i >= 0; i--) {
        long long ca = cum;
        cum += h[i];
        if (ca < k && k <= cum) { fb = base + i; rem = k - ca; }
    }
    if (fb >= 0) {
        if (mode == 0)      { scal[S_B1M] = fb; scal[S_REM1M] = (int)rem; }
        else if (mode == 1) { scal[S_B1A] = fb; scal[S_REM1A] = (int)rem; }
        else if (mode == 2) {
            int t24 = (scal[S_B1M] << 12) | fb;
            scal[S_T24M] = t24;
            float center = __uint_as_float((((unsigned)t24) << 8) | 128u);
            float lo = center - EPS_BAND;
            if (lo < 0.f) lo = 0.f;
            scal[S_BLO] = (int)__float_as_uint(lo);
            scal[S_BHI] = (int)__float_as_uint(center + EPS_BAND);
        }
        else { scal[S_T24A] = (scal[S_B1A] << 12) | fb; scal[S_JA] = (int)rem; }
    }
}

// fine histograms inside the selected coarse bins
__global__ __launch_bounds__(256) void k_hist2(const float* __restrict__ acts,
        const unsigned char* __restrict__ dead, const int* scal, int* h2m, int* h2a) {
    int b1m = scal[S_B1M], b1a = scal[S_B1A];
    int row = blockIdx.x, t = threadIdx.x;
    const float* pr = acts + (size_t)row * NS;
    for (int c = t; c < NS; c += 256) {
        unsigned bits = __float_as_uint(pr[c]);
        int hi = (int)(bits >> 20);
        if (hi == b1m) atomicAdd(&h2m[(bits >> 8) & 0xFFF], 1);
        if (b1a >= 0 && hi == b1a && dead[c]) atomicAdd(&h2a[(bits >> 8) & 0xFFF], 1);
    }
}

// single pass: exact count above band (n_hi), band-member collection, aux candidates
__global__ __launch_bounds__(256) void k_collect(const float* __restrict__ acts,
        const unsigned char* __restrict__ dead, int* scal,
        int* bandi, unsigned* cab) {
    int row = blockIdx.x, t = threadIdx.x;
    unsigned blo = (unsigned)scal[S_BLO], bhi = (unsigned)scal[S_BHI];
    int t24a = scal[S_T24A];
    const float* pr = acts + (size_t)row * NS;
    int cnt = 0;
    for (int c = t; c < NS; c += 256) {
        unsigned bits = __float_as_uint(pr[c]);
        if (bits > bhi) cnt++;
        else if (bits >= blo) {
            int p = atomicAdd(&scal[S_BANDC], 1);
            if (p < BAND_CAP) bandi[p] = row * NS + c;
        }
        if (t24a >= 0 && (bits >> 8) == (unsigned)t24a && dead[c]) {
            int p = atomicAdd(&scal[S_CCA], 1);
            if (p < CANDA_CAP) cab[p] = bits;
        }
    }
    #pragma unroll
    for (int o = 32; o > 0; o >>= 1) cnt += __shfl_down(cnt, o, 64);
    __shared__ int s2[4];
    if ((t & 63) == 0) s2[t >> 6] = cnt;
    __syncthreads();
    if (t == 0) {
        int tot = s2[0] + s2[1] + s2[2] + s2[3];
        if (tot) atomicAdd(&scal[S_NHI], tot);
    }
}

// aux threshold value from boundary-fine-bin candidates
__global__ __launch_bounds__(256) void k_resolve(const unsigned* __restrict__ cab, int* scal) {
    __shared__ int h[256];
    int t = threadIdx.x;
    h[t] = 0;
    __syncthreads();
    int t24a = scal[S_T24A];
    if (t24a < 0) { if (t == 0) scal[S_MINBITS] = 0; return; }
    int cnt = min(scal[S_CCA], CANDA_CAP);
    int ja = scal[S_JA];
    for (int e = t; e < cnt; e += 256) atomicAdd(&h[cab[e] & 0xFF], 1);
    __syncthreads();
    if (t == 0) {
        long long cum = 0; int L = 0;
        for (int b = 255; b >= 0; b--) {
            long long ca = cum; cum += h[b];
            if (ca < ja && ja <= cum) { L = b; break; }
        }
        scal[S_MINBITS] = (int)((((unsigned)t24a) << 8) | (unsigned)L);
    }
}

// fp64 recompute of band elements (exact vs reference)
__global__ __launch_bounds__(256) void k_band_re(const float* __restrict__ x,
        const float* __restrict__ b_dec, const float* __restrict__ b_enc,
        const float* __restrict__ W, const int* scal,
        const int* __restrict__ bandi, double* __restrict__ bandv) {
    int n = min(scal[S_BANDC], BAND_CAP);
    int t = threadIdx.x;
    __shared__ double sd[4];
    for (int e = blockIdx.x; e < n; e += gridDim.x) {
        int idx = bandi[e];
        int r = idx / NS, c = idx - r * NS;
        double s = 0.0;
        #pragma unroll
        for (int j = 0; j < 4; j++) {
            int d = t + j * 256;
            s += ((double)x[(size_t)r * ND + d] - (double)b_dec[d]) * (double)W[(size_t)d * NS + c];
        }
        #pragma unroll
        for (int o = 32; o > 0; o >>= 1) s += __shfl_down(s, o, 64);
        if ((t & 63) == 0) sd[t >> 6] = s;
        __syncthreads();
        if (t == 0) {
            double v = sd[0] + sd[1] + sd[2] + sd[3] + (double)b_enc[c];
            bandv[e] = fmax(v, 0.0);
        }
        __syncthreads();
    }
}

// exact selection within band: rank by (v64 desc, idx asc); keep rank < need = K - n_hi
__global__ __launch_bounds__(256) void k_band_sel(int* scal,
        const int* __restrict__ bandi, const double* __restrict__ bandv,
        int* sel_idx, unsigned* sel_bits) {
    int n = min(scal[S_BANDC], BAND_CAP);
    int need = (int)(K_MAIN - (long long)scal[S_NHI]);
    if (need < 0) need = 0;
    if (need > n) need = n;
    int t = threadIdx.x;
    for (int e = t; e < n; e += 256) {
        double v = bandv[e];
        int idx = bandi[e];
        int rank = 0;
        for (int j = 0; j < n; j++) {
            double vj = bandv[j];
            rank += (vj > v || (vj == v && bandi[j] < idx)) ? 1 : 0;
        }
        if (rank < need) {
            int p = atomicAdd(&scal[S_SELCNT], 1);
            if (p < SEL_CAP) { sel_idx[p] = idx; sel_bits[p] = __float_as_uint((float)v); }
        }
    }
}

// hierarchical sparse decode: one block per row; membership = bits > bhi OR selected band element
__global__ __launch_bounds__(256) void k_decode(const float* __restrict__ acts,
        const float* __restrict__ x, const float* __restrict__ b_dec, const float* __restrict__ Wd,
        float* __restrict__ recon, const int* scal,
        const int* __restrict__ sel_idx, double* acc) {
    int row = blockIdx.x, t = threadIdx.x;
    unsigned blo = (unsigned)scal[S_BLO], bhi = (unsigned)scal[S_BHI];
    int selcnt = min(scal[S_SELCNT], SEL_CAP);
    __shared__ int lj[2048];
    __shared__ float lv[2048];
    __shared__ int lcnt;
    __shared__ float sred[4];
    const int d0 = t * 4;
    float4 r;
    r.x = b_dec[d0]; r.y = b_dec[d0 + 1]; r.z = b_dec[d0 + 2]; r.w = b_dec[d0 + 3];
    float4 xv = *(const float4*)(x + (size_t)row * ND + d0);
    const float* arow = acts + (size_t)row * NS;
    const int bnds[5] = {0, 2048, 6144, 14336, NS};
    for (int g = 0; g < 4; g++) {
        for (int c0 = bnds[g]; c0 < bnds[g + 1]; c0 += 2048) {
            __syncthreads();
            if (t == 0) lcnt = 0;
            __syncthreads();
            #pragma unroll
            for (int u = 0; u < 8; u++) {
                int c = c0 + u * 256 + t;
                float v = arow[c];
                unsigned bits = __float_as_uint(v);
                bool keep = bits > bhi;
                if (!keep && bits >= blo) {
                    int flat = row * NS + c;
                    for (int e = 0; e < selcnt; e++)
                        if (sel_idx[e] == flat) { keep = true; break; }
                }
                if (keep) { int p = atomicAdd(&lcnt, 1); lj[p] = c; lv[p] = v; }
            }
            __syncthreads();
            int n = lcnt;
            for (int e = 0; e < n; e++) {
                float a_ = lv[e];
                float4 w = *(const float4*)(Wd + (size_t)lj[e] * ND + d0);
                r.x = fmaf(a_, w.x, r.x);
                r.y = fmaf(a_, w.y, r.y);
                r.z = fmaf(a_, w.z, r.z);
                r.w = fmaf(a_, w.w, r.w);
            }
        }
        float dx = r.x - xv.x, dy = r.y - xv.y, dz = r.z - xv.z, dw = r.w - xv.w;
        float ss = dx * dx + dy * dy + dz * dz + dw * dw;
        float tot = blk_reduce(ss, sred);
        if (t == 0) atomicAdd(&acc[A_L2_0 + g], (double)tot);
    }
    float* orow = recon + (size_t)row * ND + d0;   // region misaligned -> scalar stores
    orow[0] = r.x; orow[1] = r.y; orow[2] = r.z; orow[3] = r.w;
}

// ---- aux via dense masked GEMM ----
// pack acts_aux = relu(acts - minval) * dead into bf16 plane [NB][NS]
__global__ __launch_bounds__(256) void k_aux_pack(const float* __restrict__ acts,
        const unsigned char* __restrict__ dead, const int* scal,
        unsigned short* __restrict__ axb) {
    int row = blockIdx.x, t = threadIdx.x;
    float minval = __uint_as_float((unsigned)scal[S_MINBITS]);
    const float* arow = acts + (size_t)row * NS;
    unsigned short* orow = axb + (size_t)row * NS;
    for (int c = t; c < NS; c += 256) {
        float v = arow[c];
        float o = (dead[c] && v > minval) ? (v - minval) : 0.f;
        orow[c] = f2bf(o);
    }
}

// transpose W_dec [S][D] fp32 -> WdT [D][S] bf16
__global__ __launch_bounds__(256) void k_prep_wd(const float* __restrict__ Wd,
        unsigned short* __restrict__ WdT) {
    __shared__ float tile[32][33];
    int s0 = blockIdx.x * 32, d0 = blockIdx.y * 32;
    int t = threadIdx.x;
    int c = t & 31, r = t >> 5;
    #pragma unroll
    for (int it = 0; it < 4; it++)
        tile[r + it * 8][c] = Wd[(size_t)(s0 + r + it * 8) * ND + d0 + c];
    __syncthreads();
    int sl = t & 31, dl = t >> 5;
    #pragma unroll
    for (int it = 0; it < 4; it++)
        WdT[(size_t)(d0 + dl + it * 8) * NS + s0 + sl] = f2bf(tile[sl][dl + it * 8]);
}

// bf16 MFMA aux GEMM: raux[z] = acts_aux @ W_dec (K-split over z), per-split fp32 planes
__global__ __launch_bounds__(256) void k_aux_mfma(
        const unsigned short* __restrict__ axb, const unsigned short* __restrict__ WdT,
        float* __restrict__ raux) {
    __shared__ unsigned short As[128 * 32], Bs[128 * 32];
    const int t = threadIdx.x;
    const int lane = t & 63, w = t >> 6;
    const int wm = w >> 1, wn = w & 1;
    const int m0 = blockIdx.y * 128, n0 = blockIdx.x * 128;
    const int kbase = blockIdx.z * (NS / KSPLIT);
    const int ln15 = lane & 15, q = lane >> 4;

    f32x4 acc[4][4];
    #pragma unroll
    for (int i = 0; i < 4; i++)
        #pragma unroll
        for (int j = 0; j < 4; j++) acc[i][j] = (f32x4){0.f, 0.f, 0.f, 0.f};

    // waves 0,1 stage A halves; waves 2,3 stage B halves (64 rows x 32 cols each)
    const unsigned short* gbase;
    unsigned short* lbase;
    if (w < 2) { gbase = axb + (size_t)(m0 + w * 64) * NS; lbase = As + w * 64 * 32; }
    else       { gbase = WdT + (size_t)(n0 + (w - 2) * 64) * NS; lbase = Bs + (w - 2) * 64 * 32; }
    const unsigned short* glane = gbase + (size_t)(lane >> 2) * NS + (lane & 3) * 8 + kbase;

    for (int k0 = 0; k0 < NS / KSPLIT; k0 += 32) {
        __syncthreads();
        #pragma unroll
        for (int ch = 0; ch < 4; ch++)
            GLD16(glane + (size_t)ch * 16 * NS + k0, lbase + ch * 512);
        __syncthreads();

        bf16x8 af[4];
        #pragma unroll
        for (int i = 0; i < 4; i++)
            af[i] = *(const bf16x8*)&As[(wm * 64 + i * 16 + ln15) * 32 + q * 8];
        #pragma unroll
        for (int j = 0; j < 4; j++) {
            bf16x8 bf = *(const bf16x8*)&Bs[(wn * 64 + j * 16 + ln15) * 32 + q * 8];
            #pragma unroll
            for (int i = 0; i < 4; i++)
                acc[i][j] = __builtin_amdgcn_mfma_f32_16x16x32_bf16(af[i], bf, acc[i][j], 0, 0, 0);
        }
    }
    float* rz = raux + (size_t)blockIdx.z * NB * ND;
    #pragma unroll
    for (int j = 0; j < 4; j++) {
        int n = n0 + wn * 64 + j * 16 + ln15;
        #pragma unroll
        for (int i = 0; i < 4; i++) {
            int mrow = m0 + wm * 64 + i * 16 + q * 4;
            #pragma unroll
            for (int rg = 0; rg < 4; rg++)
                rz[(size_t)(mrow + rg) * ND + n] = acc[i][j][rg];
        }
    }
}

// aux loss: sum over B*D of (sum_z raux[z] - (x - recon))^2
__global__ __launch_bounds__(256) void k_aux_diff(const float* __restrict__ raux,
        const float* __restrict__ x, const float* __restrict__ recon, double* acc) {
    __shared__ float sred[4];
    float ss = 0.f;
    int stride = gridDim.x * blockDim.x;
    for (int i = blockIdx.x * blockDim.x + threadIdx.x; i < NB * ND; i += stride) {
        float ra = raux[i];
        #pragma unroll
        for (int z = 1; z < KSPLIT; z++) ra += raux[(size_t)z * NB * ND + i];
        float d = ra - (x[i] - recon[i]);
        ss += d * d;
    }
    float tot = blk_reduce(ss, sred);
    if (threadIdx.x == 0) atomicAdd(&acc[A_AUX], (double)tot);
}

// fallback aux: sparse gather per row
__global__ __launch_bounds__(256) void k_aux(const float* __restrict__ acts,
        const unsigned char* __restrict__ dead, const float* __restrict__ x,
        const float* __restrict__ recon, const float* __restrict__ Wd,
        const int* scal, double* acc) {
    int row = blockIdx.x, t = threadIdx.x;
    float minval = __uint_as_float((unsigned)scal[S_MINBITS]);
    __shared__ int lj[2048];
    __shared__ float lv[2048];
    __shared__ int lcnt;
    __shared__ float sred[4];
    float4 r = {0.f, 0.f, 0.f, 0.f};
    const float* arow = acts + (size_t)row * NS;
    const int d0 = t * 4;
    for (int c0 = 0; c0 < NS; c0 += 2048) {
        __syncthreads();
        if (t == 0) lcnt = 0;
        __syncthreads();
        #pragma unroll
        for (int u = 0; u < 8; u++) {
            int c = c0 + u * 256 + t;
            float v = arow[c];
            if (dead[c] && v > minval) {
                int p = atomicAdd(&lcnt, 1);
                lj[p] = c; lv[p] = v - minval;
            }
        }
        __syncthreads();
        int n = lcnt;
        for (int e = 0; e < n; e++) {
            float a_ = lv[e];
            float4 w = *(const float4*)(Wd + (size_t)lj[e] * ND + d0);
            r.x = fmaf(a_, w.x, r.x);
            r.y = fmaf(a_, w.y, r.y);
            r.z = fmaf(a_, w.z, r.z);
            r.w = fmaf(a_, w.w, r.w);
        }
    }
    const float* xr = x + (size_t)row * ND + d0;
    const float* rr = recon + (size_t)row * ND + d0;
    float dx = r.x - (xr[0] - rr[0]);
    float dy = r.y - (xr[1] - rr[1]);
    float dz = r.z - (xr[2] - rr[2]);
    float dw = r.w - (xr[3] - rr[3]);
    float ss = dx * dx + dy * dy + dz * dz + dw * dw;
    float tot = blk_reduce(ss, sred);
    if (t == 0) atomicAdd(&acc[A_AUX], (double)tot);
}

// in-place top-k zeroing over d_out acts region (strict bits > bhi) + L1/L0 for definite members
__global__ __launch_bounds__(256) void k_topk_write(float* __restrict__ out, const int* scal, double* acc, int* scalw) {
    unsigned bhi = (unsigned)scal[S_BHI];
    float l1 = 0.f;
    int cnt = 0;
    const long long vstart = 8, nvec = 15728639;   // [8, 62914564) as float4
    long long stride = (long long)gridDim.x * blockDim.x;
    for (long long i = (long long)blockIdx.x * blockDim.x + threadIdx.x; i < nvec; i += stride) {
        float4* p = (float4*)(out + vstart) + i;
        float4 v = *p;
        #define PROC(F) { unsigned b = __float_as_uint(v.F); if (b > bhi) { l1 += v.F; cnt++; } else v.F = 0.f; }
        PROC(x) PROC(y) PROC(z) PROC(w)
        #undef PROC
        *p = v;
    }
    if (blockIdx.x == 0 && threadIdx.x == 0) {
        const long long head[4] = {5, 6, 7, 62914564LL};
        for (int q = 0; q < 4; q++) {
            float v = out[head[q]];
            unsigned b = __float_as_uint(v);
            if (b > bhi) { l1 += v; cnt++; } else out[head[q]] = 0.f;
        }
    }
    int t = threadIdx.x;
    #pragma unroll
    for (int o = 32; o > 0; o >>= 1) { l1 += __shfl_down(l1, o, 64); cnt += __shfl_down(cnt, o, 64); }
    __shared__ float s1[4];
    __shared__ int s2[4];
    if ((t & 63) == 0) { s1[t >> 6] = l1; s2[t >> 6] = cnt; }
    __syncthreads();
    if (t == 0) {
        atomicAdd(&acc[A_L1], (double)(s1[0] + s1[1] + s1[2] + s1[3]));
        atomicAdd(&scalw[S_L0], s2[0] + s2[1] + s2[2] + s2[3]);
    }
}

// rewrite the selected band entries (zeroed by k_topk_write) + their L1/L0 contribution
__global__ __launch_bounds__(256) void k_selwrite(float* __restrict__ acts, const int* __restrict__ sel_idx,
        const unsigned* __restrict__ sel_bits, int* scal, double* acc) {
    int t = threadIdx.x;
    int n = min(scal[S_SELCNT], SEL_CAP);
    float l1 = 0.f;
    for (int e = t; e < n; e += 256) {
        float v = __uint_as_float(sel_bits[e]);
        acts[sel_idx[e]] = v;
        l1 += v;
    }
    #pragma unroll
    for (int o = 32; o > 0; o >>= 1) l1 += __shfl_down(l1, o, 64);
    __shared__ float s1[4];
    if ((t & 63) == 0) s1[t >> 6] = l1;
    __syncthreads();
    if (t == 0) {
        atomicAdd(&acc[A_L1], (double)(s1[0] + s1[1] + s1[2] + s1[3]));
        atomicAdd(&scal[S_L0], n);
    }
}

__global__ void k_final(float* out, const int* scal, const double* acc) {
    if (threadIdx.x == 0 && blockIdx.x == 0) {
        double ml2 = (acc[0] + acc[1] + acc[2] + acc[3]) * 0.25 / ((double)NB * ND);
        double l1 = 1e-3 * acc[A_L1] / (double)NB;
        double aux = (scal[S_NDEAD] > 0) ? (1e-2 * acc[A_AUX] / ((double)NB * ND)) : 0.0;
        out[0] = (float)(ml2 + l1 + aux);
        out[1] = (float)ml2;
        out[2] = (float)l1;
        out[3] = (float)aux;
        out[4] = (float)scal[S_L0] / (float)NB;
    }
}

// ---------------- launch ----------------
extern "C" void kernel_launch(void* const* d_in, const int* in_sizes, int n_in,
                              void* d_out, int out_size, void* d_ws, size_t ws_size,
                              hipStream_t stream) {
    const float* x     = (const float*)d_in[0];
    const float* b_dec = (const float*)d_in[1];
    const float* b_enc = (const float*)d_in[2];
    const float* W_enc = (const float*)d_in[3];
    const float* W_dec = (const float*)d_in[4];
    const int*   nbna  = (const int*)d_in[5];

    float* out = (float*)d_out;
    float* acts  = out + 5;                         // [NB, NS] (misaligned region)
    float* recon = out + 5 + (size_t)NB * NS;       // [NB, ND]

    char* ws = (char*)d_ws;
    int*    scal = (int*)(ws + OFF_SCAL);
    double* acc  = (double*)(ws + OFF_ACC);
    int*    h1m  = (int*)(ws + OFF_H1M);
    int*    h1a  = (int*)(ws + OFF_H1A);
    int*    h2m  = (int*)(ws + OFF_H2M);
    int*    h2a  = (int*)(ws + OFF_H2A);
    unsigned char* dead = (unsigned char*)(ws + OFF_DEAD);
    int*      sel_idx  = (int*)(ws + OFF_SEL_IDX);
    unsigned* sel_bits = (unsigned*)(ws + OFF_SEL_BITS);
    int*      bandi = (int*)(ws + OFF_BANDI);
    double*   bandv = (double*)(ws + OFF_BANDV);
    unsigned* cab   = (unsigned*)(ws + OFF_CAB);
    float*    raux  = (float*)(ws + OFF_RAUX);
    unsigned short* Ahg = (unsigned short*)(ws + OFF_AH);
    unsigned short* Alg = (unsigned short*)(ws + OFF_AL);
    unsigned short* WhT = (unsigned short*)(ws + OFF_WHT);
    unsigned short* WlT = (unsigned short*)(ws + OFF_WLT);
    unsigned short* axb = (unsigned short*)(ws + OFF_AXB);
    unsigned short* WdT = (unsigned short*)(ws + OFF_WDT);

    const bool use_mfma     = (ws_size >= WS_NEED_ENC);   // constant per process -> graph-stable
    const bool use_aux_gemm = (ws_size >= WS_NEED_AUX);

    k_init<<<64, 256, 0, stream>>>((int*)d_ws);
    k_dead<<<60, 256, 0, stream>>>(nbna, dead, scal);
    if (use_mfma) {
        k_prep_a<<<512, 256, 0, stream>>>(x, b_dec, Ahg, Alg);
        k_prep_w<<<dim3(NS / 32, ND / 32), 256, 0, stream>>>(W_enc, WhT, WlT);
        k_enc_mfma<<<dim3(NS / 128, NB / 128), 256, 0, stream>>>(Ahg, Alg, WhT, WlT, b_enc, acts);
    } else {
        k_enc_gemm<<<dim3(NS / GBN, NB / GBM), 256, 0, stream>>>(x, b_dec, b_enc, W_enc, acts);
    }
    k_hist1<<<1024, 256, 0, stream>>>(acts, dead, h1m, h1a);
    k_scan<<<1, 256, 0, stream>>>(h1m, scal, 0);
    k_scan<<<1, 256, 0, stream>>>(h1a, scal, 1);
    k_hist2<<<NB, 256, 0, stream>>>(acts, dead, scal, h2m, h2a);
    k_scan<<<1, 256, 0, stream>>>(h2m, scal, 2);
    k_scan<<<1, 256, 0, stream>>>(h2a, scal, 3);
    k_collect<<<NB, 256, 0, stream>>>(acts, dead, scal, bandi, cab);
    k_resolve<<<1, 256, 0, stream>>>(cab, scal);
    k_band_re<<<512, 256, 0, stream>>>(x, b_dec, b_enc, W_enc, scal, bandi, bandv);
    k_band_sel<<<1, 256, 0, stream>>>(scal, bandi, bandv, sel_idx, sel_bits);
    k_decode<<<NB, 256, 0, stream>>>(acts, x, b_dec, W_dec, recon, scal, sel_idx, acc);
    if (use_aux_gemm) {
        k_aux_pack<<<NB, 256, 0, stream>>>(acts, dead, scal, axb);
        k_prep_wd<<<dim3(NS / 32, ND / 32), 256, 0, stream>>>(W_dec, WdT);
        k_aux_mfma<<<dim3(ND / 128, NB / 128, KSPLIT), 256, 0, stream>>>(axb, WdT, raux);
        k_aux_diff<<<512, 256, 0, stream>>>(raux, x, recon, acc);
    } else {
        k_aux<<<NB, 256, 0, stream>>>(acts, dead, x, recon, W_dec, scal, acc);
    }
    k_topk_write<<<4096, 256, 0, stream>>>(out, scal, acc, scal);
    k_selwrite<<<1, 256, 0, stream>>>(acts, sel_idx, sel_bits, scal, acc);
    k_final<<<1, 64, 0, stream>>>(out, scal, acc);
}